// Round 18
// baseline (439.094 us; speedup 1.0000x reference)
//
#include <hip/hip_runtime.h>

typedef __bf16 bf16x8 __attribute__((ext_vector_type(8)));
typedef float f32x4 __attribute__((ext_vector_type(4)));
typedef unsigned int u32x4 __attribute__((ext_vector_type(4)));
typedef unsigned int u32x2 __attribute__((ext_vector_type(2)));

#define DEV static __device__ __forceinline__

DEV unsigned short f2bf(float f) {
  unsigned int u = __builtin_bit_cast(unsigned int, f);
  u += 0x7fffu + ((u >> 16) & 1u);
  return (unsigned short)(u >> 16);
}
DEV float bf2f(unsigned int hbits) { return __builtin_bit_cast(float, hbits << 16); }
DEV unsigned pack2bf(float a, float b) {  // compiler fuses to v_cvt_pk_bf16_f32
  unsigned short x = __builtin_bit_cast(unsigned short, (__bf16)a);
  unsigned short y = __builtin_bit_cast(unsigned short, (__bf16)b);
  return (unsigned)x | ((unsigned)y << 16);
}

DEV bf16x8 load_bf8(const unsigned short* p) {
  u32x4 u = *(const u32x4*)p;
  return __builtin_bit_cast(bf16x8, u);
}
DEV void unpack8(u32x4 u, float f[8]) {
  f[0] = bf2f(u.x & 0xffffu); f[1] = bf2f(u.x >> 16);
  f[2] = bf2f(u.y & 0xffffu); f[3] = bf2f(u.y >> 16);
  f[4] = bf2f(u.z & 0xffffu); f[5] = bf2f(u.z >> 16);
  f[6] = bf2f(u.w & 0xffffu); f[7] = bf2f(u.w >> 16);
}
DEV void gload_lds16(const void* g, void* l) {
  __builtin_amdgcn_global_load_lds((const __attribute__((address_space(1))) void*)g,
                                   (__attribute__((address_space(3))) void*)l, 16, 0, 0);
}
DEV f32x4 mfma16(bf16x8 a, bf16x8 b, f32x4 c) {
  return __builtin_amdgcn_mfma_f32_16x16x32_bf16(a, b, c, 0, 0, 0);
}

// ---------- fp32 -> bf16 transpose: src[K][N] -> dst[N][K] ----------
__global__ __launch_bounds__(256) void cm_transpose(
    const float* __restrict__ src, unsigned short* __restrict__ dst,
    int K, int N, long srcStrideE, long dstStrideE) {
  src += (long)blockIdx.z * srcStrideE;
  dst += (long)blockIdx.z * dstStrideE;
  __shared__ float t[32][33];
  const int n0 = blockIdx.x * 32, k0 = blockIdx.y * 32;
  const int tx = threadIdx.x & 31, ty = threadIdx.x >> 5;  // 32x8
#pragma unroll
  for (int j = 0; j < 4; ++j) {
    int k = k0 + ty + j * 8, n = n0 + tx;
    if (k < K && n < N) t[ty + j * 8][tx] = src[(long)k * N + n];
  }
  __syncthreads();
#pragma unroll
  for (int j = 0; j < 4; ++j) {
    int n = n0 + ty + j * 8, k = k0 + tx;
    if (n < N && k < K) dst[(long)n * K + k] = f2bf(t[tx][ty + j * 8]);
  }
}

// ---------- fp32 -> split bf16 (hi+lo) transpose ----------
__global__ __launch_bounds__(256) void cm_transpose_split(
    const float* __restrict__ src, unsigned short* __restrict__ dhi,
    unsigned short* __restrict__ dlo, int K, int N) {
  __shared__ float t[32][33];
  const int n0 = blockIdx.x * 32, k0 = blockIdx.y * 32;
  const int tx = threadIdx.x & 31, ty = threadIdx.x >> 5;
#pragma unroll
  for (int j = 0; j < 4; ++j) {
    int k = k0 + ty + j * 8, n = n0 + tx;
    if (k < K && n < N) t[ty + j * 8][tx] = src[(long)k * N + n];
  }
  __syncthreads();
#pragma unroll
  for (int j = 0; j < 4; ++j) {
    int n = n0 + ty + j * 8, k = k0 + tx;
    if (n < N && k < K) {
      float v = t[tx][ty + j * 8];
      unsigned short hi = f2bf(v);
      dhi[(long)n * K + k] = hi;
      dlo[(long)n * K + k] = f2bf(v - bf2f(hi));
    }
  }
}

// ---------- LayerNorm (D=1024); bf16 out, optional lo-residual bf16 out ----------
template <bool WLO>
__global__ __launch_bounds__(256) void cm_ln(
    const float* __restrict__ x, const float* __restrict__ g, const float* __restrict__ b,
    unsigned short* __restrict__ ob, unsigned short* __restrict__ olo) {
  const int row = blockIdx.x, tid = threadIdx.x;
  const f32x4 v = *(const f32x4*)(x + (long)row * 1024 + tid * 4);
  float s1 = v[0] + v[1] + v[2] + v[3];
  float s2 = v[0] * v[0] + v[1] * v[1] + v[2] * v[2] + v[3] * v[3];
#pragma unroll
  for (int m = 32; m >= 1; m >>= 1) { s1 += __shfl_xor(s1, m); s2 += __shfl_xor(s2, m); }
  __shared__ float r1[4], r2[4];
  if ((tid & 63) == 0) { r1[tid >> 6] = s1; r2[tid >> 6] = s2; }
  __syncthreads();
  s1 = r1[0] + r1[1] + r1[2] + r1[3];
  s2 = r2[0] + r2[1] + r2[2] + r2[3];
  const float mean = s1 * (1.f / 1024.f);
  const float rs = rsqrtf(s2 * (1.f / 1024.f) - mean * mean + 1e-5f);
  const f32x4 gg = *(const f32x4*)(g + tid * 4);
  const f32x4 bb = *(const f32x4*)(b + tid * 4);
  float o[4];
  unsigned short hi[4];
#pragma unroll
  for (int i = 0; i < 4; ++i) {
    o[i] = (v[i] - mean) * rs * gg[i] + bb[i];
    hi[i] = f2bf(o[i]);
  }
  u32x2 pk;
  pk.x = (unsigned)hi[0] | ((unsigned)hi[1] << 16);
  pk.y = (unsigned)hi[2] | ((unsigned)hi[3] << 16);
  *(u32x2*)(ob + (long)row * 1024 + tid * 4) = pk;
  if (WLO) {
    u32x2 pl;
    pl.x = (unsigned)f2bf(o[0] - bf2f(hi[0])) | ((unsigned)f2bf(o[1] - bf2f(hi[1])) << 16);
    pl.y = (unsigned)f2bf(o[2] - bf2f(hi[2])) | ((unsigned)f2bf(o[3] - bf2f(hi[3])) << 16);
    *(u32x2*)(olo + (long)row * 1024 + tid * 4) = pl;
  }
}

// ---------- bf16 MFMA GEMM: C[M,N] = A[M,K] * BT[N,K]^T ----------
// r16 structure (best): 128x128 tile over 512 threads (8 waves, 2x4 grid,
// 64x32 sub-tile/wave, 32-AGPR acc), BK=64 single-buffer, XOR chunk-swizzle,
// XCD swizzle (MODE==0). Partitioning for TLP beat pipelining (r5/r13/r15).
enum { EP_BF16 = 0, EP_RELU = 1, EP_GELU = 2, EP_RES_F32 = 3 };

template <int EPI, int MODE>  // MODE: 0 dense, 1 expert-gather, 2 expert-contiguous
__global__ __launch_bounds__(512, 4) void cm_gemm_bt(
    const unsigned short* __restrict__ A, int lda,
    const unsigned short* __restrict__ BT, long btStrideE, int ldb,
    const float* __restrict__ bias, int biasStrideE,
    const float* __restrict__ res,
    void* __restrict__ outp, int ldc,
    int M, int K,
    const int* __restrict__ cnt, const int* __restrict__ offs,
    const int* __restrict__ rowidx) {
  int bx, by, z;
  if (MODE == 0) {  // bijective XCD swizzle (uniform grid only)
    const int gx = gridDim.x, gy = gridDim.y;
    const int nwg = gx * gy;
    int flat = (int)blockIdx.x + gx * (int)blockIdx.y;
    const int q = nwg >> 3, r = nwg & 7, xcd = flat & 7, idx = flat >> 3;
    flat = (xcd < r ? xcd * (q + 1) : r * (q + 1) + (xcd - r) * q) + idx;
    bx = flat % gx; by = flat / gx; z = 0;
  } else {
    bx = blockIdx.x; by = blockIdx.y; z = blockIdx.z;
  }

  int valid = M, rowbase = 0;
  const unsigned short* Bp = BT;
  const float* biasp = bias;
  if (MODE > 0) {
    valid = cnt[z];
    if (by * 128 >= valid) return;
    rowbase = offs[z];
    Bp += (long)z * btStrideE;
    biasp += (long)z * biasStrideE;
  }
  const int tid = threadIdx.x;
  const int brow = by * 128, bcol = bx * 128;
  const int wid = tid >> 6, lane = tid & 63;
  const int wr = wid >> 2, wc = wid & 3;   // 2x4 wave grid; 64x32 sub-tile/wave

  const int srow0 = tid >> 3, sc = tid & 7;
  const int scg = ((sc ^ (srow0 & 7)) << 3);
  const int ldst = srow0 * 64 + sc * 8;

  __shared__ __align__(16) unsigned short As[128 * 64];
  __shared__ __align__(16) unsigned short Bs[128 * 64];

  int aoff[2];
#pragma unroll
  for (int j = 0; j < 2; ++j) {
    int m = brow + srow0 + j * 64;
    if (MODE == 0) {
      aoff[j] = m * lda;
    } else {
      int p = m < valid ? m : valid - 1;
      if (MODE == 1) aoff[j] = rowidx[z * 4096 + p] * lda;
      else           aoff[j] = (rowbase + p) * lda;
    }
  }
  const int boffl = (bcol + srow0) * ldb;

  f32x4 acc[4][2] = {};

  for (int k0 = 0; k0 < K; k0 += 64) {
#pragma unroll
    for (int j = 0; j < 2; ++j) {
      gload_lds16(A + aoff[j] + (k0 + scg), &As[ldst + j * 4096]);
      gload_lds16(Bp + boffl + (j * 64 * ldb + k0 + scg), &Bs[ldst + j * 4096]);
    }
    __syncthreads();
#pragma unroll
    for (int ks = 0; ks < 2; ++ks) {
      bf16x8 af[4], bfr[2];
#pragma unroll
      for (int m = 0; m < 4; ++m) {
        const int r = wr * 64 + m * 16 + (lane & 15);
        af[m] = load_bf8(&As[r * 64 + (((ks * 4 + (lane >> 4)) ^ (lane & 7)) << 3)]);
      }
#pragma unroll
      for (int n = 0; n < 2; ++n) {
        const int r = wc * 32 + n * 16 + (lane & 15);
        bfr[n] = load_bf8(&Bs[r * 64 + (((ks * 4 + (lane >> 4)) ^ (lane & 7)) << 3)]);
      }
#pragma unroll
      for (int m = 0; m < 4; ++m)
#pragma unroll
        for (int n = 0; n < 2; ++n)
          acc[m][n] = mfma16(af[m], bfr[n], acc[m][n]);
    }
    __syncthreads();
  }

#pragma unroll
  for (int m = 0; m < 4; ++m) {
#pragma unroll
    for (int rr = 0; rr < 4; ++rr) {
      const int lrow = brow + wr * 64 + m * 16 + (lane >> 4) * 4 + rr;
      if (MODE > 0 && lrow >= valid) continue;
      const long orow = (long)(rowbase + lrow);
#pragma unroll
      for (int n = 0; n < 2; ++n) {
        const int gcol = bcol + wc * 32 + n * 16 + (lane & 15);
        float vv = acc[m][n][rr] + biasp[gcol];
        if constexpr (EPI == EP_RELU) vv = fmaxf(vv, 0.f);
        if constexpr (EPI == EP_GELU) vv = 0.5f * vv * (1.f + erff(vv * 0.70710678f));
        if constexpr (EPI == EP_RES_F32)
          ((float*)outp)[orow * ldc + gcol] = vv + res[orow * ldc + gcol];
        else
          ((unsigned short*)outp)[orow * ldc + gcol] = f2bf(vv);
      }
    }
  }
}

// ---------- split-bf16 gate GEMM: g1f[4096,512] = relu((h_hi+h_lo)@(W_hi+W_lo)^T + b) ----------
__global__ __launch_bounds__(256, 2) void cm_gemm_gate(
    const unsigned short* __restrict__ Ah, const unsigned short* __restrict__ Al,
    const unsigned short* __restrict__ Bh, const unsigned short* __restrict__ Bl,
    const float* __restrict__ bias, float* __restrict__ C) {
  const int tid = threadIdx.x;
  const int brow = blockIdx.y * 128, bcol = blockIdx.x * 128;
  const int wid = tid >> 6, lane = tid & 63;
  const int wr = wid >> 1, wc = wid & 1;
  const int srow0 = tid >> 2, scol = (tid & 3) * 8;

  __shared__ __align__(16) unsigned short Ash[128 * 32], Asl[128 * 32];
  __shared__ __align__(16) unsigned short Bsh[128 * 32], Bsl[128 * 32];

  f32x4 acc[4][4] = {};

  for (int k0 = 0; k0 < 1024; k0 += 32) {
#pragma unroll
    for (int i = 0; i < 2; ++i) {
      const long ar = (long)(brow + srow0 + i * 64) * 1024 + k0 + scol;
      const long br = (long)(bcol + srow0 + i * 64) * 1024 + k0 + scol;
      const int lo = (srow0 + i * 64) * 32 + scol;
      gload_lds16(Ah + ar, &Ash[lo]);
      gload_lds16(Al + ar, &Asl[lo]);
      gload_lds16(Bh + br, &Bsh[lo]);
      gload_lds16(Bl + br, &Bsl[lo]);
    }
    __syncthreads();
    bf16x8 ah[4], al[4], bh[4], bl[4];
#pragma unroll
    for (int m = 0; m < 4; ++m) {
      const int ro = (wr * 64 + m * 16 + (lane & 15)) * 32 + (lane >> 4) * 8;
      ah[m] = load_bf8(&Ash[ro]); al[m] = load_bf8(&Asl[ro]);
    }
#pragma unroll
    for (int n = 0; n < 4; ++n) {
      const int ro = (wc * 64 + n * 16 + (lane & 15)) * 32 + (lane >> 4) * 8;
      bh[n] = load_bf8(&Bsh[ro]); bl[n] = load_bf8(&Bsl[ro]);
    }
#pragma unroll
    for (int m = 0; m < 4; ++m)
#pragma unroll
      for (int n = 0; n < 4; ++n) {
        acc[m][n] = mfma16(al[m], bh[n], acc[m][n]);
        acc[m][n] = mfma16(ah[m], bl[n], acc[m][n]);
        acc[m][n] = mfma16(ah[m], bh[n], acc[m][n]);
      }
    __syncthreads();
  }

#pragma unroll
  for (int m = 0; m < 4; ++m)
#pragma unroll
    for (int rr = 0; rr < 4; ++rr) {
      const long orow = brow + wr * 64 + m * 16 + (lane >> 4) * 4 + rr;
#pragma unroll
      for (int n = 0; n < 4; ++n) {
        const int gcol = bcol + wc * 64 + n * 16 + (lane & 15);
        C[orow * 512 + gcol] = fmaxf(acc[m][n][rr] + bias[gcol], 0.f);
      }
    }
}

// ---------- K/V repack: qkv[T][2560] -> Vt[bh][64][1024] (d-major) + Kp[bh][1024][64] ----------
__global__ __launch_bounds__(256) void cm_kvtrans(
    const unsigned short* __restrict__ qkv, unsigned short* __restrict__ Vt,
    unsigned short* __restrict__ Kp) {
  const int stile = blockIdx.x, bh = blockIdx.y;
  const int b = bh >> 4, h = bh & 15;
  const int tid = threadIdx.x;
  __shared__ __align__(16) unsigned short t[64][72];
  const int d0 = (tid & 7) * 8, sl = tid >> 3;
#pragma unroll
  for (int i = 0; i < 2; ++i) {
    const int s = sl + i * 32;
    const long src = (long)(b * 1024 + stile * 64 + s) * 2560 + h * 64 + d0;
    *(u32x4*)&t[s][d0] = *(const u32x4*)(qkv + src + 1536);
    *(u32x4*)(Kp + ((long)bh * 1024 + stile * 64 + s) * 64 + d0) =
        *(const u32x4*)(qkv + src + 512);
  }
  __syncthreads();
  const int s0 = (tid & 7) * 8, dl = tid >> 3;
#pragma unroll
  for (int i = 0; i < 2; ++i) {
    const int d = dl + i * 32;
    unsigned short vals[8];
#pragma unroll
    for (int j = 0; j < 8; ++j) vals[j] = t[s0 + j][d];
    u32x4 u;
    u.x = vals[0] | ((unsigned)vals[1] << 16);
    u.y = vals[2] | ((unsigned)vals[3] << 16);
    u.z = vals[4] | ((unsigned)vals[5] << 16);
    u.w = vals[6] | ((unsigned)vals[7] << 16);
    *(u32x4*)(Vt + (long)(bh * 64 + d) * 1024 + stile * 64 + s0) = u;
  }
}

// ---------- attention: per (q-tile of 64, b*h). Round-chunked unnormalized-PV ----------
// Score dbuf (1 barrier/round) + REGISTER PREFETCH: V[rnd] loaded at round top
// (hides under QK+exp), K[rnd+1] issued after QK-MFMA (hides under exp+bar+PV).
// All prefetch targets are VGPRs -> no LDS-aliasing / barrier-drain issues.
__global__ __launch_bounds__(256, 4) void cm_attn(
    const unsigned short* __restrict__ qkv,
    const unsigned short* __restrict__ Kp,
    const unsigned short* __restrict__ Vt,
    unsigned short* __restrict__ ao) {
  int flat = (int)blockIdx.x;                 // 1024 blocks
  flat = (flat & 7) * 128 + (flat >> 3);      // chunked XCD swizzle (1024 % 8 == 0)
  const int qt = flat & 15, bh = flat >> 4;
  const int b = bh >> 4, h = bh & 15, g = h >> 1;
  const int tid = threadIdx.x, wid = tid >> 6, lane = tid & 63;
  const int q0 = qt * 64;

  __shared__ __align__(16) unsigned short sc[2][64][132];  // dbuf exp(scores)
  __shared__ float rsum[4][64];
  __shared__ float rowrcp[64];

  bf16x8 bq[4][2];
#pragma unroll
  for (int nf = 0; nf < 4; ++nf)
#pragma unroll
    for (int ks = 0; ks < 2; ++ks)
      bq[nf][ks] = load_bf8(qkv + (long)(b * 1024 + q0 + nf * 16 + (lane & 15)) * 2560 +
                            g * 64 + ks * 32 + (lane >> 4) * 8);

  f32x4 oacc[4] = {};
  float ps[4] = {0.f, 0.f, 0.f, 0.f};
  const unsigned short* vtb = Vt + (long)bh * 64 * 1024;
  const unsigned short* kpb = Kp + (long)bh * 1024 * 64;

  // K register double-buffer: preload round 0
  bf16x8 akc[2][2];  // [ks][mf]
#pragma unroll
  for (int ks = 0; ks < 2; ++ks)
#pragma unroll
    for (int mf = 0; mf < 2; ++mf)
      akc[ks][mf] = load_bf8(kpb + (wid * 32 + mf * 16 + (lane & 15)) * 64 +
                             ks * 32 + (lane >> 4) * 8);

#pragma unroll 1
  for (int rnd = 0; rnd < 8; ++rnd) {
    const int cur = rnd & 1;
    // Prefetch V for THIS round now; consumed after the barrier (hides under QK+exp)
    bf16x8 bv[4];
#pragma unroll
    for (int kc = 0; kc < 4; ++kc)
      bv[kc] = load_bf8(vtb + (long)(wid * 16 + (lane & 15)) * 1024 +
                        rnd * 128 + kc * 32 + (lane >> 4) * 8);
    // QK with preloaded K fragments
    f32x4 acc[2][4] = {};
#pragma unroll
    for (int ks = 0; ks < 2; ++ks)
#pragma unroll
      for (int mf = 0; mf < 2; ++mf)
#pragma unroll
        for (int nf = 0; nf < 4; ++nf)
          acc[mf][nf] = mfma16(akc[ks][mf], bq[nf][ks], acc[mf][nf]);
    // Prefetch K for NEXT round (hides under exp + barrier + PV)
    bf16x8 akn[2][2];
    if (rnd + 1 < 8) {
#pragma unroll
      for (int ks = 0; ks < 2; ++ks)
#pragma unroll
        for (int mf = 0; mf < 2; ++mf)
          akn[ks][mf] = load_bf8(kpb + ((rnd + 1) * 128 + wid * 32 + mf * 16 +
                                        (lane & 15)) * 64 + ks * 32 + (lane >> 4) * 8);
    } else {
#pragma unroll
      for (int ks = 0; ks < 2; ++ks)
#pragma unroll
        for (int mf = 0; mf < 2; ++mf)
          akn[ks][mf] = akc[ks][mf];
    }
    // exp -> sc[cur] + register row-sum partials
#pragma unroll
    for (int mf = 0; mf < 2; ++mf)
#pragma unroll
      for (int nf = 0; nf < 4; ++nf) {
        const int q = nf * 16 + (lane & 15);
        const int kl = wid * 32 + mf * 16 + (lane >> 4) * 4;
        float e0 = __expf(acc[mf][nf][0] * 0.125f);
        float e1 = __expf(acc[mf][nf][1] * 0.125f);
        float e2 = __expf(acc[mf][nf][2] * 0.125f);
        float e3 = __expf(acc[mf][nf][3] * 0.125f);
        ps[nf] += (e0 + e1) + (e2 + e3);
        u32x2 pk;
        pk.x = pack2bf(e0, e1);
        pk.y = pack2bf(e2, e3);
        *(u32x2*)&sc[cur][q][kl] = pk;
      }
    __syncthreads();  // sc[cur] complete; also orders rnd's writes vs rnd-1's reads
    // PV with prefetched V registers
#pragma unroll
    for (int kc = 0; kc < 4; ++kc) {
#pragma unroll
      for (int m = 0; m < 4; ++m) {
        const bf16x8 ap = load_bf8(&sc[cur][m * 16 + (lane & 15)][kc * 32 + (lane >> 4) * 8]);
        oacc[m] = mfma16(ap, bv[kc], oacc[m]);
      }
    }
    // rotate K register buffer
#pragma unroll
    for (int ks = 0; ks < 2; ++ks)
#pragma unroll
      for (int mf = 0; mf < 2; ++mf)
        akc[ks][mf] = akn[ks][mf];
    // no barrier: next round writes sc[cur^1]
  }
  __syncthreads();

#pragma unroll
  for (int nf = 0; nf < 4; ++nf) {
    ps[nf] += __shfl_xor(ps[nf], 16);
    ps[nf] += __shfl_xor(ps[nf], 32);
  }
  if (lane < 16) {
#pragma unroll
    for (int nf = 0; nf < 4; ++nf) rsum[wid][lane + nf * 16] = ps[nf];
  }
  __syncthreads();
  if (tid < 64)
    rowrcp[tid] = 1.f / (rsum[0][tid] + rsum[1][tid] + rsum[2][tid] + rsum[3][tid]);
  __syncthreads();

#pragma unroll
  for (int m = 0; m < 4; ++m)
#pragma unroll
    for (int rr = 0; rr < 4; ++rr) {
      const int q = m * 16 + (lane >> 4) * 4 + rr;
      const int d = wid * 16 + (lane & 15);
      ao[(long)(b * 1024 + q0 + q) * 1024 + h * 64 + d] = f2bf(oacc[m][rr] * rowrcp[q]);
    }
}

// ---------- routing pick: gate-2 GEMV + softmax + top2 + renorm (NO atomics) ----------
__global__ __launch_bounds__(64) void cm_route_pick(
    const float* __restrict__ g1f, const float* __restrict__ gw2, const float* __restrict__ gb2,
    int* __restrict__ pick, int* __restrict__ slot_e, float* __restrict__ rwt) {
  const int t = blockIdx.x, lane = threadIdx.x;
  f32x4 a0 = *(const f32x4*)(g1f + (long)t * 512 + lane * 8);
  f32x4 a1 = *(const f32x4*)(g1f + (long)t * 512 + lane * 8 + 4);
  float logit[8];
#pragma unroll
  for (int e = 0; e < 8; ++e) {
    float s = 0.f;
#pragma unroll
    for (int j = 0; j < 4; ++j) {
      s += a0[j] * gw2[(lane * 8 + j) * 8 + e];
      s += a1[j] * gw2[(lane * 8 + 4 + j) * 8 + e];
    }
#pragma unroll
    for (int m = 32; m >= 1; m >>= 1) s += __shfl_xor(s, m);
    logit[e] = s + gb2[e];
  }
  float mx = logit[0];
#pragma unroll
  for (int e = 1; e < 8; ++e) mx = fmaxf(mx, logit[e]);
  float p[8], sum = 0.f;
#pragma unroll
  for (int e = 0; e < 8; ++e) { p[e] = __expf(logit[e] - mx); sum += p[e]; }
  const float rs = 1.f / sum;
#pragma unroll
  for (int e = 0; e < 8; ++e) p[e] *= rs;
  int i0 = 0;
#pragma unroll
  for (int e = 1; e < 8; ++e) if (p[e] > p[i0]) i0 = e;
  int i1 = (i0 == 0) ? 1 : 0;
#pragma unroll
  for (int e = 0; e < 8; ++e) if (e != i0 && p[e] > p[i1]) i1 = e;
  // reference: softmax AGAIN over the top-k *probabilities*
  const float w0 = 1.f / (1.f + __expf(p[i1] - p[i0]));
  if (lane == 0) {
    pick[t] = i0 | (i1 << 8);
    slot_e[t * 2] = i0; slot_e[t * 2 + 1] = i1;
    rwt[t * 2] = w0;    rwt[t * 2 + 1] = 1.f - w0;
  }
}

// ---------- routing place: wave-aggregated histogram + scatter (8 atomics/wave) ----------
__global__ __launch_bounds__(256) void cm_route_place(
    const int* __restrict__ pick, int* __restrict__ cnt,
    int* __restrict__ etok, int* __restrict__ slot_p) {
  const int t = blockIdx.x * 256 + threadIdx.x;
  const int lane = threadIdx.x & 63;
  const int pk = pick[t];
  const int p0 = pk & 15, p1 = (pk >> 8) & 15;
  const unsigned long long lt = ((unsigned long long)1 << lane) - 1;
  int my_r0 = 0, my_c0p1 = 0, my_r1 = 0, tot = 0;
#pragma unroll
  for (int e = 0; e < 8; ++e) {
    const unsigned long long m0 = __ballot(p0 == e);
    const unsigned long long m1 = __ballot(p1 == e);
    if (p0 == e) my_r0 = __popcll(m0 & lt);
    if (p1 == e) { my_c0p1 = __popcll(m0); my_r1 = __popcll(m1 & lt); }
    if (lane == e) tot = __popcll(m0) + __popcll(m1);
  }
  int base = 0;
  if (lane < 8 && tot > 0) base = atomicAdd(&cnt[lane], tot);
  const int b0 = __shfl(base, p0);
  const int b1 = __shfl(base, p1);
  const int pos0 = b0 + my_r0;
  const int pos1 = b1 + my_c0p1 + my_r1;
  etok[p0 * 4096 + pos0] = t;
  etok[p1 * 4096 + pos1] = t;
  slot_p[t * 2] = pos0;
  slot_p[t * 2 + 1] = pos1;
}

__global__ void cm_offs(const int* __restrict__ cnt, int* __restrict__ offs) {
  if (threadIdx.x == 0) {
    int s = 0;
#pragma unroll
    for (int e = 0; e < 8; ++e) { offs[e] = s; s += cnt[e]; }
  }
}

// ---------- combine: out = x2 + w0*eo[slot0] + w1*eo[slot1] ----------
__global__ __launch_bounds__(256) void cm_combine(
    const float* __restrict__ x2, const unsigned short* __restrict__ eo,
    const int* __restrict__ slot_e, const int* __restrict__ slot_p,
    const float* __restrict__ rwt, const int* __restrict__ offs,
    float* __restrict__ outp) {
  const int t = blockIdx.x, tid = threadIdx.x;
  const long r0 = (long)(offs[slot_e[t * 2]] + slot_p[t * 2]);
  const long r1 = (long)(offs[slot_e[t * 2 + 1]] + slot_p[t * 2 + 1]);
  const float w0 = rwt[t * 2], w1 = rwt[t * 2 + 1];
  const f32x4 xv = *(const f32x4*)(x2 + (long)t * 1024 + tid * 4);
  u32x2 u0 = *(const u32x2*)(eo + r0 * 1024 + tid * 4);
  u32x2 u1 = *(const u32x2*)(eo + r1 * 1024 + tid * 4);
  f32x4 o;
  o[0] = xv[0] + w0 * bf2f(u0.x & 0xffffu) + w1 * bf2f(u1.x & 0xffffu);
  o[1] = xv[1] + w0 * bf2f(u0.x >> 16) + w1 * bf2f(u1.x >> 16);
  o[2] = xv[2] + w0 * bf2f(u0.y & 0xffffu) + w1 * bf2f(u1.y & 0xffffu);
  o[3] = xv[3] + w0 * bf2f(u0.y >> 16) + w1 * bf2f(u1.y >> 16);
  *(f32x4*)(outp + (long)t * 1024 + tid * 4) = o;
}

extern "C" void kernel_launch(void* const* d_in, const int* in_sizes, int n_in,
                              void* d_out, int out_size, void* d_ws, size_t ws_size,
                              hipStream_t stream) {
  if (n_in < 21) return;
  const float* x    = (const float*)d_in[0];
  const float* wq   = (const float*)d_in[1];
  const float* bq   = (const float*)d_in[2];
  const float* wk   = (const float*)d_in[3];
  const float* bk   = (const float*)d_in[4];
  const float* wv   = (const float*)d_in[5];
  const float* bv   = (const float*)d_in[6];
  const float* wo   = (const float*)d_in[7];
  const float* bo   = (const float*)d_in[8];
  const float* ln1g = (const float*)d_in[9];
  const float* ln1b = (const float*)d_in[10];
  const float* ln2g = (const float*)d_in[11];
  const float* ln2b = (const float*)d_in[12];
  const float* gw1  = (const float*)d_in[13];
  const float* gb1  = (const float*)d_in[14];
  const float* gw2  = (const float*)d_in[15];
  const float* gb2  = (const float*)d_in[16];
  const float* ew1  = (const float*)d_in[17];
  const float* eb1  = (const float*)d_in[18];
  const float* ew2  = (const float*)d_in[19];
  const float* eb2  = (const float*)d_in[20];
  float* outp = (float*)d_out;

  char* ws = (char*)d_ws;
  size_t off = 0;
  auto carve = [&](size_t bytes) -> char* {
    char* p = ws + off;
    off += (bytes + 255) & ~(size_t)255;
    return p;
  };
  unsigned short* wqkvT = (unsigned short*)carve(2560l * 1024 * 2);
  unsigned short* woT   = (unsigned short*)carve(1024l * 1024 * 2);
  unsigned short* gw1hT = (unsigned short*)carve(512l * 1024 * 2);
  unsigned short* gw1lT = (unsigned short*)carve(512l * 1024 * 2);
  unsigned short* ew1T  = (unsigned short*)carve(8l * 2048 * 1024 * 2);
  unsigned short* ew2T  = (unsigned short*)carve(8l * 1024 * 2048 * 2);
  float* bqkv           = (float*)carve(2560 * 4);
  unsigned short* hbuf  = (unsigned short*)carve(4096l * 1024 * 2);
  unsigned short* qkvl  = (unsigned short*)carve(4096l * 2560 * 2);
  unsigned short* Vt    = (unsigned short*)carve(4096l * 1024 * 2);
  unsigned short* Kp    = (unsigned short*)carve(4096l * 1024 * 2);
  unsigned short* ao    = (unsigned short*)carve(4096l * 1024 * 2);
  unsigned short* h2    = (unsigned short*)carve(4096l * 1024 * 2);
  unsigned short* h2lo  = (unsigned short*)carve(4096l * 1024 * 2);
  int* cnt              = (int*)carve(8 * 4);
  int* offs             = (int*)carve(8 * 4);
  int* etok             = (int*)carve(8l * 4096 * 4);
  int* slot_e           = (int*)carve(8192 * 4);
  int* slot_p           = (int*)carve(8192 * 4);
  float* rwt            = (float*)carve(8192 * 4);
  int* pick             = (int*)carve(4096 * 4);
  unsigned short* hid   = (unsigned short*)carve(8192l * 2048 * 2);
  unsigned short* eo    = (unsigned short*)carve(8192l * 1024 * 2);
  if (off > ws_size) return;  // workspace too small -> fail loudly via validation
  float* x2 = outp;           // residual-1 result lives in d_out (rewritten every call)
  // dead-buffer reuse: Vt (8 MB) is consumed by cm_attn; gate hidden fp32 needs exactly 8 MB
  float* g1f = (float*)Vt;    // [4096][512] fp32 gate hidden

  (void)hipMemsetAsync(cnt, 0, 8 * 4, stream);
  (void)hipMemcpyAsync(bqkv, (const void*)bq, 512 * 4, hipMemcpyDeviceToDevice, stream);
  (void)hipMemcpyAsync(bqkv + 512, (const void*)bk, 1024 * 4, hipMemcpyDeviceToDevice, stream);
  (void)hipMemcpyAsync(bqkv + 1536, (const void*)bv, 1024 * 4, hipMemcpyDeviceToDevice, stream);

  cm_transpose<<<dim3(16, 32, 1), 256, 0, stream>>>(wq, wqkvT, 1024, 512, 0l, 0l);
  cm_transpose<<<dim3(32, 32, 1), 256, 0, stream>>>(wk, wqkvT + 512l * 1024, 1024, 1024, 0l, 0l);
  cm_transpose<<<dim3(32, 32, 1), 256, 0, stream>>>(wv, wqkvT + 1536l * 1024, 1024, 1024, 0l, 0l);
  cm_transpose<<<dim3(32, 32, 1), 256, 0, stream>>>(wo, woT, 1024, 1024, 0l, 0l);
  cm_transpose_split<<<dim3(16, 32, 1), 256, 0, stream>>>(gw1, gw1hT, gw1lT, 1024, 512);
  cm_transpose<<<dim3(64, 32, 8), 256, 0, stream>>>(ew1, ew1T, 1024, 2048, 1024l * 2048, 2048l * 1024);
  cm_transpose<<<dim3(32, 64, 8), 256, 0, stream>>>(ew2, ew2T, 2048, 1024, 2048l * 1024, 1024l * 2048);

  cm_ln<false><<<4096, 256, 0, stream>>>(x, ln1g, ln1b, hbuf, nullptr);
  cm_gemm_bt<EP_BF16, 0><<<dim3(20, 32, 1), 512, 0, stream>>>(
      hbuf, 1024, wqkvT, 0l, 1024, bqkv, 0, nullptr, qkvl, 2560, 4096, 1024,
      nullptr, nullptr, nullptr);
  cm_kvtrans<<<dim3(16, 64, 1), 256, 0, stream>>>(qkvl, Vt, Kp);
  cm_attn<<<dim3(1024, 1, 1), 256, 0, stream>>>(qkvl, Kp, Vt, ao);
  cm_gemm_bt<EP_RES_F32, 0><<<dim3(8, 32, 1), 512, 0, stream>>>(
      ao, 1024, woT, 0l, 1024, bo, 0, x, x2, 1024, 4096, 1024,
      nullptr, nullptr, nullptr);
  cm_ln<true><<<4096, 256, 0, stream>>>(x2, ln2g, ln2b, h2, h2lo);

  // --- gate: split-bf16 MFMA GEMM (near-fp32 accuracy), pick + aggregated place ---
  cm_gemm_gate<<<dim3(4, 32, 1), 256, 0, stream>>>(h2, h2lo, gw1hT, gw1lT, gb1, g1f);
  cm_route_pick<<<4096, 64, 0, stream>>>(g1f, gw2, gb2, pick, slot_e, rwt);
  cm_route_place<<<16, 256, 0, stream>>>(pick, cnt, etok, slot_p);
  cm_offs<<<1, 64, 0, stream>>>(cnt, offs);

  cm_gemm_bt<EP_GELU, 1><<<dim3(16, 32, 8), 512, 0, stream>>>(
      h2, 1024, ew1T, 2048l * 1024, 1024, eb1, 2048, nullptr, hid, 2048, 4096, 1024,
      cnt, offs, etok);
  cm_gemm_bt<EP_BF16, 2><<<dim3(8, 32, 8), 512, 0, stream>>>(
      hid, 2048, ew2T, 1024l * 2048, 2048, eb2, 1024, nullptr, eo, 1024, 4096, 2048,
      cnt, offs, nullptr);
  cm_combine<<<4096, 256, 0, stream>>>(x2, eo, slot_e, slot_p, rwt, offs, outp);
}

// Round 19
// 427.611 us; speedup vs baseline: 1.0269x; 1.0269x over previous
//
#include <hip/hip_runtime.h>

typedef __bf16 bf16x8 __attribute__((ext_vector_type(8)));
typedef float f32x4 __attribute__((ext_vector_type(4)));
typedef unsigned int u32x4 __attribute__((ext_vector_type(4)));
typedef unsigned int u32x2 __attribute__((ext_vector_type(2)));

#define DEV static __device__ __forceinline__

DEV unsigned short f2bf(float f) {
  unsigned int u = __builtin_bit_cast(unsigned int, f);
  u += 0x7fffu + ((u >> 16) & 1u);
  return (unsigned short)(u >> 16);
}
DEV float bf2f(unsigned int hbits) { return __builtin_bit_cast(float, hbits << 16); }
DEV unsigned pack2bf(float a, float b) {  // compiler fuses to v_cvt_pk_bf16_f32
  unsigned short x = __builtin_bit_cast(unsigned short, (__bf16)a);
  unsigned short y = __builtin_bit_cast(unsigned short, (__bf16)b);
  return (unsigned)x | ((unsigned)y << 16);
}

DEV bf16x8 load_bf8(const unsigned short* p) {
  u32x4 u = *(const u32x4*)p;
  return __builtin_bit_cast(bf16x8, u);
}
DEV void unpack8(u32x4 u, float f[8]) {
  f[0] = bf2f(u.x & 0xffffu); f[1] = bf2f(u.x >> 16);
  f[2] = bf2f(u.y & 0xffffu); f[3] = bf2f(u.y >> 16);
  f[4] = bf2f(u.z & 0xffffu); f[5] = bf2f(u.z >> 16);
  f[6] = bf2f(u.w & 0xffffu); f[7] = bf2f(u.w >> 16);
}
DEV void gload_lds16(const void* g, void* l) {
  __builtin_amdgcn_global_load_lds((const __attribute__((address_space(1))) void*)g,
                                   (__attribute__((address_space(3))) void*)l, 16, 0, 0);
}
DEV f32x4 mfma16(bf16x8 a, bf16x8 b, f32x4 c) {
  return __builtin_amdgcn_mfma_f32_16x16x32_bf16(a, b, c, 0, 0, 0);
}

// ---------- fp32 -> bf16 transpose: src[K][N] -> dst[N][K] ----------
__global__ __launch_bounds__(256) void cm_transpose(
    const float* __restrict__ src, unsigned short* __restrict__ dst,
    int K, int N, long srcStrideE, long dstStrideE) {
  src += (long)blockIdx.z * srcStrideE;
  dst += (long)blockIdx.z * dstStrideE;
  __shared__ float t[32][33];
  const int n0 = blockIdx.x * 32, k0 = blockIdx.y * 32;
  const int tx = threadIdx.x & 31, ty = threadIdx.x >> 5;  // 32x8
#pragma unroll
  for (int j = 0; j < 4; ++j) {
    int k = k0 + ty + j * 8, n = n0 + tx;
    if (k < K && n < N) t[ty + j * 8][tx] = src[(long)k * N + n];
  }
  __syncthreads();
#pragma unroll
  for (int j = 0; j < 4; ++j) {
    int n = n0 + ty + j * 8, k = k0 + tx;
    if (n < N && k < K) dst[(long)n * K + k] = f2bf(t[tx][ty + j * 8]);
  }
}

// ---------- fp32 -> split bf16 (hi+lo) transpose ----------
__global__ __launch_bounds__(256) void cm_transpose_split(
    const float* __restrict__ src, unsigned short* __restrict__ dhi,
    unsigned short* __restrict__ dlo, int K, int N) {
  __shared__ float t[32][33];
  const int n0 = blockIdx.x * 32, k0 = blockIdx.y * 32;
  const int tx = threadIdx.x & 31, ty = threadIdx.x >> 5;
#pragma unroll
  for (int j = 0; j < 4; ++j) {
    int k = k0 + ty + j * 8, n = n0 + tx;
    if (k < K && n < N) t[ty + j * 8][tx] = src[(long)k * N + n];
  }
  __syncthreads();
#pragma unroll
  for (int j = 0; j < 4; ++j) {
    int n = n0 + ty + j * 8, k = k0 + tx;
    if (n < N && k < K) {
      float v = t[tx][ty + j * 8];
      unsigned short hi = f2bf(v);
      dhi[(long)n * K + k] = hi;
      dlo[(long)n * K + k] = f2bf(v - bf2f(hi));
    }
  }
}

// ---------- LayerNorm (D=1024); bf16 out, optional lo-residual bf16 out ----------
template <bool WLO>
__global__ __launch_bounds__(256) void cm_ln(
    const float* __restrict__ x, const float* __restrict__ g, const float* __restrict__ b,
    unsigned short* __restrict__ ob, unsigned short* __restrict__ olo) {
  const int row = blockIdx.x, tid = threadIdx.x;
  const f32x4 v = *(const f32x4*)(x + (long)row * 1024 + tid * 4);
  float s1 = v[0] + v[1] + v[2] + v[3];
  float s2 = v[0] * v[0] + v[1] * v[1] + v[2] * v[2] + v[3] * v[3];
#pragma unroll
  for (int m = 32; m >= 1; m >>= 1) { s1 += __shfl_xor(s1, m); s2 += __shfl_xor(s2, m); }
  __shared__ float r1[4], r2[4];
  if ((tid & 63) == 0) { r1[tid >> 6] = s1; r2[tid >> 6] = s2; }
  __syncthreads();
  s1 = r1[0] + r1[1] + r1[2] + r1[3];
  s2 = r2[0] + r2[1] + r2[2] + r2[3];
  const float mean = s1 * (1.f / 1024.f);
  const float rs = rsqrtf(s2 * (1.f / 1024.f) - mean * mean + 1e-5f);
  const f32x4 gg = *(const f32x4*)(g + tid * 4);
  const f32x4 bb = *(const f32x4*)(b + tid * 4);
  float o[4];
  unsigned short hi[4];
#pragma unroll
  for (int i = 0; i < 4; ++i) {
    o[i] = (v[i] - mean) * rs * gg[i] + bb[i];
    hi[i] = f2bf(o[i]);
  }
  u32x2 pk;
  pk.x = (unsigned)hi[0] | ((unsigned)hi[1] << 16);
  pk.y = (unsigned)hi[2] | ((unsigned)hi[3] << 16);
  *(u32x2*)(ob + (long)row * 1024 + tid * 4) = pk;
  if (WLO) {
    u32x2 pl;
    pl.x = (unsigned)f2bf(o[0] - bf2f(hi[0])) | ((unsigned)f2bf(o[1] - bf2f(hi[1])) << 16);
    pl.y = (unsigned)f2bf(o[2] - bf2f(hi[2])) | ((unsigned)f2bf(o[3] - bf2f(hi[3])) << 16);
    *(u32x2*)(olo + (long)row * 1024 + tid * 4) = pl;
  }
}

// ---------- bf16 MFMA GEMM: C[M,N] = A[M,K] * BT[N,K]^T ----------
// r16 structure (best): 128x128 tile over 512 threads (8 waves, 2x4 grid,
// 64x32 sub-tile/wave, 32-AGPR acc), BK=64 single-buffer, XOR chunk-swizzle,
// XCD swizzle (MODE==0). Partitioning for TLP beat pipelining (r5/r13/r15).
enum { EP_BF16 = 0, EP_RELU = 1, EP_GELU = 2, EP_RES_F32 = 3 };

template <int EPI, int MODE>  // MODE: 0 dense, 1 expert-gather, 2 expert-contiguous
__global__ __launch_bounds__(512, 4) void cm_gemm_bt(
    const unsigned short* __restrict__ A, int lda,
    const unsigned short* __restrict__ BT, long btStrideE, int ldb,
    const float* __restrict__ bias, int biasStrideE,
    const float* __restrict__ res,
    void* __restrict__ outp, int ldc,
    int M, int K,
    const int* __restrict__ cnt, const int* __restrict__ offs,
    const int* __restrict__ rowidx) {
  int bx, by, z;
  if (MODE == 0) {  // bijective XCD swizzle (uniform grid only)
    const int gx = gridDim.x, gy = gridDim.y;
    const int nwg = gx * gy;
    int flat = (int)blockIdx.x + gx * (int)blockIdx.y;
    const int q = nwg >> 3, r = nwg & 7, xcd = flat & 7, idx = flat >> 3;
    flat = (xcd < r ? xcd * (q + 1) : r * (q + 1) + (xcd - r) * q) + idx;
    bx = flat % gx; by = flat / gx; z = 0;
  } else {
    bx = blockIdx.x; by = blockIdx.y; z = blockIdx.z;
  }

  int valid = M, rowbase = 0;
  const unsigned short* Bp = BT;
  const float* biasp = bias;
  if (MODE > 0) {
    valid = cnt[z];
    if (by * 128 >= valid) return;
    rowbase = offs[z];
    Bp += (long)z * btStrideE;
    biasp += (long)z * biasStrideE;
  }
  const int tid = threadIdx.x;
  const int brow = by * 128, bcol = bx * 128;
  const int wid = tid >> 6, lane = tid & 63;
  const int wr = wid >> 2, wc = wid & 3;   // 2x4 wave grid; 64x32 sub-tile/wave

  const int srow0 = tid >> 3, sc = tid & 7;
  const int scg = ((sc ^ (srow0 & 7)) << 3);
  const int ldst = srow0 * 64 + sc * 8;

  __shared__ __align__(16) unsigned short As[128 * 64];
  __shared__ __align__(16) unsigned short Bs[128 * 64];

  int aoff[2];
#pragma unroll
  for (int j = 0; j < 2; ++j) {
    int m = brow + srow0 + j * 64;
    if (MODE == 0) {
      aoff[j] = m * lda;
    } else {
      int p = m < valid ? m : valid - 1;
      if (MODE == 1) aoff[j] = rowidx[z * 4096 + p] * lda;
      else           aoff[j] = (rowbase + p) * lda;
    }
  }
  const int boffl = (bcol + srow0) * ldb;

  f32x4 acc[4][2] = {};

  for (int k0 = 0; k0 < K; k0 += 64) {
#pragma unroll
    for (int j = 0; j < 2; ++j) {
      gload_lds16(A + aoff[j] + (k0 + scg), &As[ldst + j * 4096]);
      gload_lds16(Bp + boffl + (j * 64 * ldb + k0 + scg), &Bs[ldst + j * 4096]);
    }
    __syncthreads();
#pragma unroll
    for (int ks = 0; ks < 2; ++ks) {
      bf16x8 af[4], bfr[2];
#pragma unroll
      for (int m = 0; m < 4; ++m) {
        const int r = wr * 64 + m * 16 + (lane & 15);
        af[m] = load_bf8(&As[r * 64 + (((ks * 4 + (lane >> 4)) ^ (lane & 7)) << 3)]);
      }
#pragma unroll
      for (int n = 0; n < 2; ++n) {
        const int r = wc * 32 + n * 16 + (lane & 15);
        bfr[n] = load_bf8(&Bs[r * 64 + (((ks * 4 + (lane >> 4)) ^ (lane & 7)) << 3)]);
      }
#pragma unroll
      for (int m = 0; m < 4; ++m)
#pragma unroll
        for (int n = 0; n < 2; ++n)
          acc[m][n] = mfma16(af[m], bfr[n], acc[m][n]);
    }
    __syncthreads();
  }

#pragma unroll
  for (int m = 0; m < 4; ++m) {
#pragma unroll
    for (int rr = 0; rr < 4; ++rr) {
      const int lrow = brow + wr * 64 + m * 16 + (lane >> 4) * 4 + rr;
      if (MODE > 0 && lrow >= valid) continue;
      const long orow = (long)(rowbase + lrow);
#pragma unroll
      for (int n = 0; n < 2; ++n) {
        const int gcol = bcol + wc * 32 + n * 16 + (lane & 15);
        float vv = acc[m][n][rr] + biasp[gcol];
        if constexpr (EPI == EP_RELU) vv = fmaxf(vv, 0.f);
        if constexpr (EPI == EP_GELU) vv = 0.5f * vv * (1.f + erff(vv * 0.70710678f));
        if constexpr (EPI == EP_RES_F32)
          ((float*)outp)[orow * ldc + gcol] = vv + res[orow * ldc + gcol];
        else
          ((unsigned short*)outp)[orow * ldc + gcol] = f2bf(vv);
      }
    }
  }
}

// ---------- split-bf16 gate GEMM: g1f[4096,512] = relu((h_hi+h_lo)@(W_hi+W_lo)^T + b) ----------
__global__ __launch_bounds__(256, 2) void cm_gemm_gate(
    const unsigned short* __restrict__ Ah, const unsigned short* __restrict__ Al,
    const unsigned short* __restrict__ Bh, const unsigned short* __restrict__ Bl,
    const float* __restrict__ bias, float* __restrict__ C) {
  const int tid = threadIdx.x;
  const int brow = blockIdx.y * 128, bcol = blockIdx.x * 128;
  const int wid = tid >> 6, lane = tid & 63;
  const int wr = wid >> 1, wc = wid & 1;
  const int srow0 = tid >> 2, scol = (tid & 3) * 8;

  __shared__ __align__(16) unsigned short Ash[128 * 32], Asl[128 * 32];
  __shared__ __align__(16) unsigned short Bsh[128 * 32], Bsl[128 * 32];

  f32x4 acc[4][4] = {};

  for (int k0 = 0; k0 < 1024; k0 += 32) {
#pragma unroll
    for (int i = 0; i < 2; ++i) {
      const long ar = (long)(brow + srow0 + i * 64) * 1024 + k0 + scol;
      const long br = (long)(bcol + srow0 + i * 64) * 1024 + k0 + scol;
      const int lo = (srow0 + i * 64) * 32 + scol;
      gload_lds16(Ah + ar, &Ash[lo]);
      gload_lds16(Al + ar, &Asl[lo]);
      gload_lds16(Bh + br, &Bsh[lo]);
      gload_lds16(Bl + br, &Bsl[lo]);
    }
    __syncthreads();
    bf16x8 ah[4], al[4], bh[4], bl[4];
#pragma unroll
    for (int m = 0; m < 4; ++m) {
      const int ro = (wr * 64 + m * 16 + (lane & 15)) * 32 + (lane >> 4) * 8;
      ah[m] = load_bf8(&Ash[ro]); al[m] = load_bf8(&Asl[ro]);
    }
#pragma unroll
    for (int n = 0; n < 4; ++n) {
      const int ro = (wc * 64 + n * 16 + (lane & 15)) * 32 + (lane >> 4) * 8;
      bh[n] = load_bf8(&Bsh[ro]); bl[n] = load_bf8(&Bsl[ro]);
    }
#pragma unroll
    for (int m = 0; m < 4; ++m)
#pragma unroll
      for (int n = 0; n < 4; ++n) {
        acc[m][n] = mfma16(al[m], bh[n], acc[m][n]);
        acc[m][n] = mfma16(ah[m], bl[n], acc[m][n]);
        acc[m][n] = mfma16(ah[m], bh[n], acc[m][n]);
      }
    __syncthreads();
  }

#pragma unroll
  for (int m = 0; m < 4; ++m)
#pragma unroll
    for (int rr = 0; rr < 4; ++rr) {
      const long orow = brow + wr * 64 + m * 16 + (lane >> 4) * 4 + rr;
#pragma unroll
      for (int n = 0; n < 4; ++n) {
        const int gcol = bcol + wc * 64 + n * 16 + (lane & 15);
        C[orow * 512 + gcol] = fmaxf(acc[m][n][rr] + bias[gcol], 0.f);
      }
    }
}

// ---------- K/V repack: qkv[T][2560] -> Vt[bh][64][1024] (d-major) + Kp[bh][1024][64] ----------
__global__ __launch_bounds__(256) void cm_kvtrans(
    const unsigned short* __restrict__ qkv, unsigned short* __restrict__ Vt,
    unsigned short* __restrict__ Kp) {
  const int stile = blockIdx.x, bh = blockIdx.y;
  const int b = bh >> 4, h = bh & 15;
  const int tid = threadIdx.x;
  __shared__ __align__(16) unsigned short t[64][72];
  const int d0 = (tid & 7) * 8, sl = tid >> 3;
#pragma unroll
  for (int i = 0; i < 2; ++i) {
    const int s = sl + i * 32;
    const long src = (long)(b * 1024 + stile * 64 + s) * 2560 + h * 64 + d0;
    *(u32x4*)&t[s][d0] = *(const u32x4*)(qkv + src + 1536);
    *(u32x4*)(Kp + ((long)bh * 1024 + stile * 64 + s) * 64 + d0) =
        *(const u32x4*)(qkv + src + 512);
  }
  __syncthreads();
  const int s0 = (tid & 7) * 8, dl = tid >> 3;
#pragma unroll
  for (int i = 0; i < 2; ++i) {
    const int d = dl + i * 32;
    unsigned short vals[8];
#pragma unroll
    for (int j = 0; j < 8; ++j) vals[j] = t[s0 + j][d];
    u32x4 u;
    u.x = vals[0] | ((unsigned)vals[1] << 16);
    u.y = vals[2] | ((unsigned)vals[3] << 16);
    u.z = vals[4] | ((unsigned)vals[5] << 16);
    u.w = vals[6] | ((unsigned)vals[7] << 16);
    *(u32x4*)(Vt + (long)(bh * 64 + d) * 1024 + stile * 64 + s0) = u;
  }
}

// ---------- attention: per (q-tile of 64, b*h). Round-chunked unnormalized-PV ----------
// Score dbuf (1 barrier/round) + V-ONLY register prefetch (16 transient VGPRs;
// r18's persistent K dbuf spilled to scratch — WRITE_SIZE 9->22 MB — and lost).
__global__ __launch_bounds__(256, 4) void cm_attn(
    const unsigned short* __restrict__ qkv,
    const unsigned short* __restrict__ Kp,
    const unsigned short* __restrict__ Vt,
    unsigned short* __restrict__ ao) {
  int flat = (int)blockIdx.x;                 // 1024 blocks
  flat = (flat & 7) * 128 + (flat >> 3);      // chunked XCD swizzle (1024 % 8 == 0)
  const int qt = flat & 15, bh = flat >> 4;
  const int b = bh >> 4, h = bh & 15, g = h >> 1;
  const int tid = threadIdx.x, wid = tid >> 6, lane = tid & 63;
  const int q0 = qt * 64;

  __shared__ __align__(16) unsigned short sc[2][64][132];  // dbuf exp(scores)
  __shared__ float rsum[4][64];
  __shared__ float rowrcp[64];

  bf16x8 bq[4][2];
#pragma unroll
  for (int nf = 0; nf < 4; ++nf)
#pragma unroll
    for (int ks = 0; ks < 2; ++ks)
      bq[nf][ks] = load_bf8(qkv + (long)(b * 1024 + q0 + nf * 16 + (lane & 15)) * 2560 +
                            g * 64 + ks * 32 + (lane >> 4) * 8);

  f32x4 oacc[4] = {};
  float ps[4] = {0.f, 0.f, 0.f, 0.f};
  const unsigned short* vtb = Vt + (long)bh * 64 * 1024;
  const unsigned short* kpb = Kp + (long)bh * 1024 * 64;

#pragma unroll 1
  for (int rnd = 0; rnd < 8; ++rnd) {
    const int cur = rnd & 1;
    // Prefetch V for THIS round (consumed after the barrier; hides under QK+exp)
    bf16x8 bv[4];
#pragma unroll
    for (int kc = 0; kc < 4; ++kc)
      bv[kc] = load_bf8(vtb + (long)(wid * 16 + (lane & 15)) * 1024 +
                        rnd * 128 + kc * 32 + (lane >> 4) * 8);
    // QK: K loaded in place (r17 structure — no persistent K buffer, no spills)
    {
      const int kb = rnd * 128 + wid * 32;
      f32x4 acc[2][4] = {};
#pragma unroll
      for (int ks = 0; ks < 2; ++ks) {
        bf16x8 ak[2];
#pragma unroll
        for (int mf = 0; mf < 2; ++mf)
          ak[mf] = load_bf8(kpb + (kb + mf * 16 + (lane & 15)) * 64 +
                            ks * 32 + (lane >> 4) * 8);
#pragma unroll
        for (int mf = 0; mf < 2; ++mf)
#pragma unroll
          for (int nf = 0; nf < 4; ++nf)
            acc[mf][nf] = mfma16(ak[mf], bq[nf][ks], acc[mf][nf]);
      }
      // exp -> sc[cur] + register row-sum partials
#pragma unroll
      for (int mf = 0; mf < 2; ++mf)
#pragma unroll
        for (int nf = 0; nf < 4; ++nf) {
          const int q = nf * 16 + (lane & 15);
          const int kl = wid * 32 + mf * 16 + (lane >> 4) * 4;
          float e0 = __expf(acc[mf][nf][0] * 0.125f);
          float e1 = __expf(acc[mf][nf][1] * 0.125f);
          float e2 = __expf(acc[mf][nf][2] * 0.125f);
          float e3 = __expf(acc[mf][nf][3] * 0.125f);
          ps[nf] += (e0 + e1) + (e2 + e3);
          u32x2 pk;
          pk.x = pack2bf(e0, e1);
          pk.y = pack2bf(e2, e3);
          *(u32x2*)&sc[cur][q][kl] = pk;
        }
    }
    __syncthreads();  // sc[cur] complete; also orders rnd's writes vs rnd-1's reads
    // PV with prefetched V registers
#pragma unroll
    for (int kc = 0; kc < 4; ++kc) {
#pragma unroll
      for (int m = 0; m < 4; ++m) {
        const bf16x8 ap = load_bf8(&sc[cur][m * 16 + (lane & 15)][kc * 32 + (lane >> 4) * 8]);
        oacc[m] = mfma16(ap, bv[kc], oacc[m]);
      }
    }
    // no barrier: next round writes sc[cur^1]
  }
  __syncthreads();

#pragma unroll
  for (int nf = 0; nf < 4; ++nf) {
    ps[nf] += __shfl_xor(ps[nf], 16);
    ps[nf] += __shfl_xor(ps[nf], 32);
  }
  if (lane < 16) {
#pragma unroll
    for (int nf = 0; nf < 4; ++nf) rsum[wid][lane + nf * 16] = ps[nf];
  }
  __syncthreads();
  if (tid < 64)
    rowrcp[tid] = 1.f / (rsum[0][tid] + rsum[1][tid] + rsum[2][tid] + rsum[3][tid]);
  __syncthreads();

#pragma unroll
  for (int m = 0; m < 4; ++m)
#pragma unroll
    for (int rr = 0; rr < 4; ++rr) {
      const int q = m * 16 + (lane >> 4) * 4 + rr;
      const int d = wid * 16 + (lane & 15);
      ao[(long)(b * 1024 + q0 + q) * 1024 + h * 64 + d] = f2bf(oacc[m][rr] * rowrcp[q]);
    }
}

// ---------- routing pick: gate-2 GEMV + softmax + top2 + renorm (NO atomics) ----------
__global__ __launch_bounds__(64) void cm_route_pick(
    const float* __restrict__ g1f, const float* __restrict__ gw2, const float* __restrict__ gb2,
    int* __restrict__ pick, int* __restrict__ slot_e, float* __restrict__ rwt) {
  const int t = blockIdx.x, lane = threadIdx.x;
  f32x4 a0 = *(const f32x4*)(g1f + (long)t * 512 + lane * 8);
  f32x4 a1 = *(const f32x4*)(g1f + (long)t * 512 + lane * 8 + 4);
  float logit[8];
#pragma unroll
  for (int e = 0; e < 8; ++e) {
    float s = 0.f;
#pragma unroll
    for (int j = 0; j < 4; ++j) {
      s += a0[j] * gw2[(lane * 8 + j) * 8 + e];
      s += a1[j] * gw2[(lane * 8 + 4 + j) * 8 + e];
    }
#pragma unroll
    for (int m = 32; m >= 1; m >>= 1) s += __shfl_xor(s, m);
    logit[e] = s + gb2[e];
  }
  float mx = logit[0];
#pragma unroll
  for (int e = 1; e < 8; ++e) mx = fmaxf(mx, logit[e]);
  float p[8], sum = 0.f;
#pragma unroll
  for (int e = 0; e < 8; ++e) { p[e] = __expf(logit[e] - mx); sum += p[e]; }
  const float rs = 1.f / sum;
#pragma unroll
  for (int e = 0; e < 8; ++e) p[e] *= rs;
  int i0 = 0;
#pragma unroll
  for (int e = 1; e < 8; ++e) if (p[e] > p[i0]) i0 = e;
  int i1 = (i0 == 0) ? 1 : 0;
#pragma unroll
  for (int e = 0; e < 8; ++e) if (e != i0 && p[e] > p[i1]) i1 = e;
  // reference: softmax AGAIN over the top-k *probabilities*
  const float w0 = 1.f / (1.f + __expf(p[i1] - p[i0]));
  if (lane == 0) {
    pick[t] = i0 | (i1 << 8);
    slot_e[t * 2] = i0; slot_e[t * 2 + 1] = i1;
    rwt[t * 2] = w0;    rwt[t * 2 + 1] = 1.f - w0;
  }
}

// ---------- routing place: wave-aggregated histogram + scatter (8 atomics/wave) ----------
__global__ __launch_bounds__(256) void cm_route_place(
    const int* __restrict__ pick, int* __restrict__ cnt,
    int* __restrict__ etok, int* __restrict__ slot_p) {
  const int t = blockIdx.x * 256 + threadIdx.x;
  const int lane = threadIdx.x & 63;
  const int pk = pick[t];
  const int p0 = pk & 15, p1 = (pk >> 8) & 15;
  const unsigned long long lt = ((unsigned long long)1 << lane) - 1;
  int my_r0 = 0, my_c0p1 = 0, my_r1 = 0, tot = 0;
#pragma unroll
  for (int e = 0; e < 8; ++e) {
    const unsigned long long m0 = __ballot(p0 == e);
    const unsigned long long m1 = __ballot(p1 == e);
    if (p0 == e) my_r0 = __popcll(m0 & lt);
    if (p1 == e) { my_c0p1 = __popcll(m0); my_r1 = __popcll(m1 & lt); }
    if (lane == e) tot = __popcll(m0) + __popcll(m1);
  }
  int base = 0;
  if (lane < 8 && tot > 0) base = atomicAdd(&cnt[lane], tot);
  const int b0 = __shfl(base, p0);
  const int b1 = __shfl(base, p1);
  const int pos0 = b0 + my_r0;
  const int pos1 = b1 + my_c0p1 + my_r1;
  etok[p0 * 4096 + pos0] = t;
  etok[p1 * 4096 + pos1] = t;
  slot_p[t * 2] = pos0;
  slot_p[t * 2 + 1] = pos1;
}

__global__ void cm_offs(const int* __restrict__ cnt, int* __restrict__ offs) {
  if (threadIdx.x == 0) {
    int s = 0;
#pragma unroll
    for (int e = 0; e < 8; ++e) { offs[e] = s; s += cnt[e]; }
  }
}

// ---------- combine: out = x2 + w0*eo[slot0] + w1*eo[slot1] ----------
__global__ __launch_bounds__(256) void cm_combine(
    const float* __restrict__ x2, const unsigned short* __restrict__ eo,
    const int* __restrict__ slot_e, const int* __restrict__ slot_p,
    const float* __restrict__ rwt, const int* __restrict__ offs,
    float* __restrict__ outp) {
  const int t = blockIdx.x, tid = threadIdx.x;
  const long r0 = (long)(offs[slot_e[t * 2]] + slot_p[t * 2]);
  const long r1 = (long)(offs[slot_e[t * 2 + 1]] + slot_p[t * 2 + 1]);
  const float w0 = rwt[t * 2], w1 = rwt[t * 2 + 1];
  const f32x4 xv = *(const f32x4*)(x2 + (long)t * 1024 + tid * 4);
  u32x2 u0 = *(const u32x2*)(eo + r0 * 1024 + tid * 4);
  u32x2 u1 = *(const u32x2*)(eo + r1 * 1024 + tid * 4);
  f32x4 o;
  o[0] = xv[0] + w0 * bf2f(u0.x & 0xffffu) + w1 * bf2f(u1.x & 0xffffu);
  o[1] = xv[1] + w0 * bf2f(u0.x >> 16) + w1 * bf2f(u1.x >> 16);
  o[2] = xv[2] + w0 * bf2f(u0.y & 0xffffu) + w1 * bf2f(u1.y & 0xffffu);
  o[3] = xv[3] + w0 * bf2f(u0.y >> 16) + w1 * bf2f(u1.y >> 16);
  *(f32x4*)(outp + (long)t * 1024 + tid * 4) = o;
}

extern "C" void kernel_launch(void* const* d_in, const int* in_sizes, int n_in,
                              void* d_out, int out_size, void* d_ws, size_t ws_size,
                              hipStream_t stream) {
  if (n_in < 21) return;
  const float* x    = (const float*)d_in[0];
  const float* wq   = (const float*)d_in[1];
  const float* bq   = (const float*)d_in[2];
  const float* wk   = (const float*)d_in[3];
  const float* bk   = (const float*)d_in[4];
  const float* wv   = (const float*)d_in[5];
  const float* bv   = (const float*)d_in[6];
  const float* wo   = (const float*)d_in[7];
  const float* bo   = (const float*)d_in[8];
  const float* ln1g = (const float*)d_in[9];
  const float* ln1b = (const float*)d_in[10];
  const float* ln2g = (const float*)d_in[11];
  const float* ln2b = (const float*)d_in[12];
  const float* gw1  = (const float*)d_in[13];
  const float* gb1  = (const float*)d_in[14];
  const float* gw2  = (const float*)d_in[15];
  const float* gb2  = (const float*)d_in[16];
  const float* ew1  = (const float*)d_in[17];
  const float* eb1  = (const float*)d_in[18];
  const float* ew2  = (const float*)d_in[19];
  const float* eb2  = (const float*)d_in[20];
  float* outp = (float*)d_out;

  char* ws = (char*)d_ws;
  size_t off = 0;
  auto carve = [&](size_t bytes) -> char* {
    char* p = ws + off;
    off += (bytes + 255) & ~(size_t)255;
    return p;
  };
  unsigned short* wqkvT = (unsigned short*)carve(2560l * 1024 * 2);
  unsigned short* woT   = (unsigned short*)carve(1024l * 1024 * 2);
  unsigned short* gw1hT = (unsigned short*)carve(512l * 1024 * 2);
  unsigned short* gw1lT = (unsigned short*)carve(512l * 1024 * 2);
  unsigned short* ew1T  = (unsigned short*)carve(8l * 2048 * 1024 * 2);
  unsigned short* ew2T  = (unsigned short*)carve(8l * 1024 * 2048 * 2);
  float* bqkv           = (float*)carve(2560 * 4);
  unsigned short* hbuf  = (unsigned short*)carve(4096l * 1024 * 2);
  unsigned short* qkvl  = (unsigned short*)carve(4096l * 2560 * 2);
  unsigned short* Vt    = (unsigned short*)carve(4096l * 1024 * 2);
  unsigned short* Kp    = (unsigned short*)carve(4096l * 1024 * 2);
  unsigned short* ao    = (unsigned short*)carve(4096l * 1024 * 2);
  unsigned short* h2    = (unsigned short*)carve(4096l * 1024 * 2);
  unsigned short* h2lo  = (unsigned short*)carve(4096l * 1024 * 2);
  int* cnt              = (int*)carve(8 * 4);
  int* offs             = (int*)carve(8 * 4);
  int* etok             = (int*)carve(8l * 4096 * 4);
  int* slot_e           = (int*)carve(8192 * 4);
  int* slot_p           = (int*)carve(8192 * 4);
  float* rwt            = (float*)carve(8192 * 4);
  int* pick             = (int*)carve(4096 * 4);
  unsigned short* hid   = (unsigned short*)carve(8192l * 2048 * 2);
  unsigned short* eo    = (unsigned short*)carve(8192l * 1024 * 2);
  if (off > ws_size) return;  // workspace too small -> fail loudly via validation
  float* x2 = outp;           // residual-1 result lives in d_out (rewritten every call)
  // dead-buffer reuse: Vt (8 MB) is consumed by cm_attn; gate hidden fp32 needs exactly 8 MB
  float* g1f = (float*)Vt;    // [4096][512] fp32 gate hidden

  (void)hipMemsetAsync(cnt, 0, 8 * 4, stream);
  (void)hipMemcpyAsync(bqkv, (const void*)bq, 512 * 4, hipMemcpyDeviceToDevice, stream);
  (void)hipMemcpyAsync(bqkv + 512, (const void*)bk, 1024 * 4, hipMemcpyDeviceToDevice, stream);
  (void)hipMemcpyAsync(bqkv + 1536, (const void*)bv, 1024 * 4, hipMemcpyDeviceToDevice, stream);

  cm_transpose<<<dim3(16, 32, 1), 256, 0, stream>>>(wq, wqkvT, 1024, 512, 0l, 0l);
  cm_transpose<<<dim3(32, 32, 1), 256, 0, stream>>>(wk, wqkvT + 512l * 1024, 1024, 1024, 0l, 0l);
  cm_transpose<<<dim3(32, 32, 1), 256, 0, stream>>>(wv, wqkvT + 1536l * 1024, 1024, 1024, 0l, 0l);
  cm_transpose<<<dim3(32, 32, 1), 256, 0, stream>>>(wo, woT, 1024, 1024, 0l, 0l);
  cm_transpose_split<<<dim3(16, 32, 1), 256, 0, stream>>>(gw1, gw1hT, gw1lT, 1024, 512);
  cm_transpose<<<dim3(64, 32, 8), 256, 0, stream>>>(ew1, ew1T, 1024, 2048, 1024l * 2048, 2048l * 1024);
  cm_transpose<<<dim3(32, 64, 8), 256, 0, stream>>>(ew2, ew2T, 2048, 1024, 2048l * 1024, 1024l * 2048);

  cm_ln<false><<<4096, 256, 0, stream>>>(x, ln1g, ln1b, hbuf, nullptr);
  cm_gemm_bt<EP_BF16, 0><<<dim3(20, 32, 1), 512, 0, stream>>>(
      hbuf, 1024, wqkvT, 0l, 1024, bqkv, 0, nullptr, qkvl, 2560, 4096, 1024,
      nullptr, nullptr, nullptr);
  cm_kvtrans<<<dim3(16, 64, 1), 256, 0, stream>>>(qkvl, Vt, Kp);
  cm_attn<<<dim3(1024, 1, 1), 256, 0, stream>>>(qkvl, Kp, Vt, ao);
  cm_gemm_bt<EP_RES_F32, 0><<<dim3(8, 32, 1), 512, 0, stream>>>(
      ao, 1024, woT, 0l, 1024, bo, 0, x, x2, 1024, 4096, 1024,
      nullptr, nullptr, nullptr);
  cm_ln<true><<<4096, 256, 0, stream>>>(x2, ln2g, ln2b, h2, h2lo);

  // --- gate: split-bf16 MFMA GEMM (near-fp32 accuracy), pick + aggregated place ---
  cm_gemm_gate<<<dim3(4, 32, 1), 256, 0, stream>>>(h2, h2lo, gw1hT, gw1lT, gb1, g1f);
  cm_route_pick<<<4096, 64, 0, stream>>>(g1f, gw2, gb2, pick, slot_e, rwt);
  cm_route_place<<<16, 256, 0, stream>>>(pick, cnt, etok, slot_p);
  cm_offs<<<1, 64, 0, stream>>>(cnt, offs);

  cm_gemm_bt<EP_GELU, 1><<<dim3(16, 32, 8), 512, 0, stream>>>(
      h2, 1024, ew1T, 2048l * 1024, 1024, eb1, 2048, nullptr, hid, 2048, 4096, 1024,
      cnt, offs, etok);
  cm_gemm_bt<EP_BF16, 2><<<dim3(8, 32, 8), 512, 0, stream>>>(
      hid, 2048, ew2T, 1024l * 2048, 2048, eb2, 1024, nullptr, eo, 1024, 4096, 2048,
      cnt, offs, nullptr);
  cm_combine<<<4096, 256, 0, stream>>>(x2, eo, slot_e, slot_p, rwt, offs, outp);
}

// Round 20
// 423.220 us; speedup vs baseline: 1.0375x; 1.0104x over previous
//
#include <hip/hip_runtime.h>

typedef __bf16 bf16x8 __attribute__((ext_vector_type(8)));
typedef float f32x4 __attribute__((ext_vector_type(4)));
typedef unsigned int u32x4 __attribute__((ext_vector_type(4)));
typedef unsigned int u32x2 __attribute__((ext_vector_type(2)));

#define DEV static __device__ __forceinline__

DEV unsigned short f2bf(float f) {
  unsigned int u = __builtin_bit_cast(unsigned int, f);
  u += 0x7fffu + ((u >> 16) & 1u);
  return (unsigned short)(u >> 16);
}
DEV float bf2f(unsigned int hbits) { return __builtin_bit_cast(float, hbits << 16); }
DEV unsigned pack2bf(float a, float b) {  // compiler fuses to v_cvt_pk_bf16_f32
  unsigned short x = __builtin_bit_cast(unsigned short, (__bf16)a);
  unsigned short y = __builtin_bit_cast(unsigned short, (__bf16)b);
  return (unsigned)x | ((unsigned)y << 16);
}

DEV bf16x8 load_bf8(const unsigned short* p) {
  u32x4 u = *(const u32x4*)p;
  return __builtin_bit_cast(bf16x8, u);
}
DEV void unpack8(u32x4 u, float f[8]) {
  f[0] = bf2f(u.x & 0xffffu); f[1] = bf2f(u.x >> 16);
  f[2] = bf2f(u.y & 0xffffu); f[3] = bf2f(u.y >> 16);
  f[4] = bf2f(u.z & 0xffffu); f[5] = bf2f(u.z >> 16);
  f[6] = bf2f(u.w & 0xffffu); f[7] = bf2f(u.w >> 16);
}
DEV void gload_lds16(const void* g, void* l) {
  __builtin_amdgcn_global_load_lds((const __attribute__((address_space(1))) void*)g,
                                   (__attribute__((address_space(3))) void*)l, 16, 0, 0);
}
DEV f32x4 mfma16(bf16x8 a, bf16x8 b, f32x4 c) {
  return __builtin_amdgcn_mfma_f32_16x16x32_bf16(a, b, c, 0, 0, 0);
}

// ---------- fp32 -> bf16 transpose: src[K][N] -> dst[N][K] ----------
__global__ __launch_bounds__(256) void cm_transpose(
    const float* __restrict__ src, unsigned short* __restrict__ dst,
    int K, int N, long srcStrideE, long dstStrideE) {
  src += (long)blockIdx.z * srcStrideE;
  dst += (long)blockIdx.z * dstStrideE;
  __shared__ float t[32][33];
  const int n0 = blockIdx.x * 32, k0 = blockIdx.y * 32;
  const int tx = threadIdx.x & 31, ty = threadIdx.x >> 5;  // 32x8
#pragma unroll
  for (int j = 0; j < 4; ++j) {
    int k = k0 + ty + j * 8, n = n0 + tx;
    if (k < K && n < N) t[ty + j * 8][tx] = src[(long)k * N + n];
  }
  __syncthreads();
#pragma unroll
  for (int j = 0; j < 4; ++j) {
    int n = n0 + ty + j * 8, k = k0 + tx;
    if (n < N && k < K) dst[(long)n * K + k] = f2bf(t[tx][ty + j * 8]);
  }
}

// ---------- fp32 -> split bf16 (hi+lo) transpose ----------
__global__ __launch_bounds__(256) void cm_transpose_split(
    const float* __restrict__ src, unsigned short* __restrict__ dhi,
    unsigned short* __restrict__ dlo, int K, int N) {
  __shared__ float t[32][33];
  const int n0 = blockIdx.x * 32, k0 = blockIdx.y * 32;
  const int tx = threadIdx.x & 31, ty = threadIdx.x >> 5;
#pragma unroll
  for (int j = 0; j < 4; ++j) {
    int k = k0 + ty + j * 8, n = n0 + tx;
    if (k < K && n < N) t[ty + j * 8][tx] = src[(long)k * N + n];
  }
  __syncthreads();
#pragma unroll
  for (int j = 0; j < 4; ++j) {
    int n = n0 + ty + j * 8, k = k0 + tx;
    if (n < N && k < K) {
      float v = t[tx][ty + j * 8];
      unsigned short hi = f2bf(v);
      dhi[(long)n * K + k] = hi;
      dlo[(long)n * K + k] = f2bf(v - bf2f(hi));
    }
  }
}

// ---------- LayerNorm (D=1024); bf16 out, optional lo-residual bf16 out ----------
template <bool WLO>
__global__ __launch_bounds__(256) void cm_ln(
    const float* __restrict__ x, const float* __restrict__ g, const float* __restrict__ b,
    unsigned short* __restrict__ ob, unsigned short* __restrict__ olo) {
  const int row = blockIdx.x, tid = threadIdx.x;
  const f32x4 v = *(const f32x4*)(x + (long)row * 1024 + tid * 4);
  float s1 = v[0] + v[1] + v[2] + v[3];
  float s2 = v[0] * v[0] + v[1] * v[1] + v[2] * v[2] + v[3] * v[3];
#pragma unroll
  for (int m = 32; m >= 1; m >>= 1) { s1 += __shfl_xor(s1, m); s2 += __shfl_xor(s2, m); }
  __shared__ float r1[4], r2[4];
  if ((tid & 63) == 0) { r1[tid >> 6] = s1; r2[tid >> 6] = s2; }
  __syncthreads();
  s1 = r1[0] + r1[1] + r1[2] + r1[3];
  s2 = r2[0] + r2[1] + r2[2] + r2[3];
  const float mean = s1 * (1.f / 1024.f);
  const float rs = rsqrtf(s2 * (1.f / 1024.f) - mean * mean + 1e-5f);
  const f32x4 gg = *(const f32x4*)(g + tid * 4);
  const f32x4 bb = *(const f32x4*)(b + tid * 4);
  float o[4];
  unsigned short hi[4];
#pragma unroll
  for (int i = 0; i < 4; ++i) {
    o[i] = (v[i] - mean) * rs * gg[i] + bb[i];
    hi[i] = f2bf(o[i]);
  }
  u32x2 pk;
  pk.x = (unsigned)hi[0] | ((unsigned)hi[1] << 16);
  pk.y = (unsigned)hi[2] | ((unsigned)hi[3] << 16);
  *(u32x2*)(ob + (long)row * 1024 + tid * 4) = pk;
  if (WLO) {
    u32x2 pl;
    pl.x = (unsigned)f2bf(o[0] - bf2f(hi[0])) | ((unsigned)f2bf(o[1] - bf2f(hi[1])) << 16);
    pl.y = (unsigned)f2bf(o[2] - bf2f(hi[2])) | ((unsigned)f2bf(o[3] - bf2f(hi[3])) << 16);
    *(u32x2*)(olo + (long)row * 1024 + tid * 4) = pl;
  }
}

// ---------- bf16 MFMA GEMM: C[M,N] = A[M,K] * BT[N,K]^T ----------
// r16 structure (best): 128x128 tile over 512 threads (8 waves, 2x4 grid,
// 64x32 sub-tile/wave, 32-AGPR acc), BK=64 single-buffer, XOR chunk-swizzle,
// XCD swizzle (MODE==0). Partitioning for TLP beat pipelining (r5/r13/r15).
enum { EP_BF16 = 0, EP_RELU = 1, EP_GELU = 2, EP_RES_F32 = 3 };

template <int EPI, int MODE>  // MODE: 0 dense, 1 expert-gather, 2 expert-contiguous
__global__ __launch_bounds__(512, 4) void cm_gemm_bt(
    const unsigned short* __restrict__ A, int lda,
    const unsigned short* __restrict__ BT, long btStrideE, int ldb,
    const float* __restrict__ bias, int biasStrideE,
    const float* __restrict__ res,
    void* __restrict__ outp, int ldc,
    int M, int K,
    const int* __restrict__ cnt, const int* __restrict__ offs,
    const int* __restrict__ rowidx) {
  int bx, by, z;
  if (MODE == 0) {  // bijective XCD swizzle (uniform grid only)
    const int gx = gridDim.x, gy = gridDim.y;
    const int nwg = gx * gy;
    int flat = (int)blockIdx.x + gx * (int)blockIdx.y;
    const int q = nwg >> 3, r = nwg & 7, xcd = flat & 7, idx = flat >> 3;
    flat = (xcd < r ? xcd * (q + 1) : r * (q + 1) + (xcd - r) * q) + idx;
    bx = flat % gx; by = flat / gx; z = 0;
  } else {
    bx = blockIdx.x; by = blockIdx.y; z = blockIdx.z;
  }

  int valid = M, rowbase = 0;
  const unsigned short* Bp = BT;
  const float* biasp = bias;
  if (MODE > 0) {
    valid = cnt[z];
    if (by * 128 >= valid) return;
    rowbase = offs[z];
    Bp += (long)z * btStrideE;
    biasp += (long)z * biasStrideE;
  }
  const int tid = threadIdx.x;
  const int brow = by * 128, bcol = bx * 128;
  const int wid = tid >> 6, lane = tid & 63;
  const int wr = wid >> 2, wc = wid & 3;   // 2x4 wave grid; 64x32 sub-tile/wave

  const int srow0 = tid >> 3, sc = tid & 7;
  const int scg = ((sc ^ (srow0 & 7)) << 3);
  const int ldst = srow0 * 64 + sc * 8;

  __shared__ __align__(16) unsigned short As[128 * 64];
  __shared__ __align__(16) unsigned short Bs[128 * 64];

  int aoff[2];
#pragma unroll
  for (int j = 0; j < 2; ++j) {
    int m = brow + srow0 + j * 64;
    if (MODE == 0) {
      aoff[j] = m * lda;
    } else {
      int p = m < valid ? m : valid - 1;
      if (MODE == 1) aoff[j] = rowidx[z * 4096 + p] * lda;
      else           aoff[j] = (rowbase + p) * lda;
    }
  }
  const int boffl = (bcol + srow0) * ldb;

  f32x4 acc[4][2] = {};

  for (int k0 = 0; k0 < K; k0 += 64) {
#pragma unroll
    for (int j = 0; j < 2; ++j) {
      gload_lds16(A + aoff[j] + (k0 + scg), &As[ldst + j * 4096]);
      gload_lds16(Bp + boffl + (j * 64 * ldb + k0 + scg), &Bs[ldst + j * 4096]);
    }
    __syncthreads();
#pragma unroll
    for (int ks = 0; ks < 2; ++ks) {
      bf16x8 af[4], bfr[2];
#pragma unroll
      for (int m = 0; m < 4; ++m) {
        const int r = wr * 64 + m * 16 + (lane & 15);
        af[m] = load_bf8(&As[r * 64 + (((ks * 4 + (lane >> 4)) ^ (lane & 7)) << 3)]);
      }
#pragma unroll
      for (int n = 0; n < 2; ++n) {
        const int r = wc * 32 + n * 16 + (lane & 15);
        bfr[n] = load_bf8(&Bs[r * 64 + (((ks * 4 + (lane >> 4)) ^ (lane & 7)) << 3)]);
      }
#pragma unroll
      for (int m = 0; m < 4; ++m)
#pragma unroll
        for (int n = 0; n < 2; ++n)
          acc[m][n] = mfma16(af[m], bfr[n], acc[m][n]);
    }
    __syncthreads();
  }

#pragma unroll
  for (int m = 0; m < 4; ++m) {
#pragma unroll
    for (int rr = 0; rr < 4; ++rr) {
      const int lrow = brow + wr * 64 + m * 16 + (lane >> 4) * 4 + rr;
      if (MODE > 0 && lrow >= valid) continue;
      const long orow = (long)(rowbase + lrow);
#pragma unroll
      for (int n = 0; n < 2; ++n) {
        const int gcol = bcol + wc * 32 + n * 16 + (lane & 15);
        float vv = acc[m][n][rr] + biasp[gcol];
        if constexpr (EPI == EP_RELU) vv = fmaxf(vv, 0.f);
        if constexpr (EPI == EP_GELU) vv = 0.5f * vv * (1.f + erff(vv * 0.70710678f));
        if constexpr (EPI == EP_RES_F32)
          ((float*)outp)[orow * ldc + gcol] = vv + res[orow * ldc + gcol];
        else
          ((unsigned short*)outp)[orow * ldc + gcol] = f2bf(vv);
      }
    }
  }
}

// ---------- split-bf16 gate GEMM: g1f[4096,512] = relu((h_hi+h_lo)@(W_hi+W_lo)^T + b) ----------
__global__ __launch_bounds__(256, 2) void cm_gemm_gate(
    const unsigned short* __restrict__ Ah, const unsigned short* __restrict__ Al,
    const unsigned short* __restrict__ Bh, const unsigned short* __restrict__ Bl,
    const float* __restrict__ bias, float* __restrict__ C) {
  const int tid = threadIdx.x;
  const int brow = blockIdx.y * 128, bcol = blockIdx.x * 128;
  const int wid = tid >> 6, lane = tid & 63;
  const int wr = wid >> 1, wc = wid & 1;
  const int srow0 = tid >> 2, scol = (tid & 3) * 8;

  __shared__ __align__(16) unsigned short Ash[128 * 32], Asl[128 * 32];
  __shared__ __align__(16) unsigned short Bsh[128 * 32], Bsl[128 * 32];

  f32x4 acc[4][4] = {};

  for (int k0 = 0; k0 < 1024; k0 += 32) {
#pragma unroll
    for (int i = 0; i < 2; ++i) {
      const long ar = (long)(brow + srow0 + i * 64) * 1024 + k0 + scol;
      const long br = (long)(bcol + srow0 + i * 64) * 1024 + k0 + scol;
      const int lo = (srow0 + i * 64) * 32 + scol;
      gload_lds16(Ah + ar, &Ash[lo]);
      gload_lds16(Al + ar, &Asl[lo]);
      gload_lds16(Bh + br, &Bsh[lo]);
      gload_lds16(Bl + br, &Bsl[lo]);
    }
    __syncthreads();
    bf16x8 ah[4], al[4], bh[4], bl[4];
#pragma unroll
    for (int m = 0; m < 4; ++m) {
      const int ro = (wr * 64 + m * 16 + (lane & 15)) * 32 + (lane >> 4) * 8;
      ah[m] = load_bf8(&Ash[ro]); al[m] = load_bf8(&Asl[ro]);
    }
#pragma unroll
    for (int n = 0; n < 4; ++n) {
      const int ro = (wc * 64 + n * 16 + (lane & 15)) * 32 + (lane >> 4) * 8;
      bh[n] = load_bf8(&Bsh[ro]); bl[n] = load_bf8(&Bsl[ro]);
    }
#pragma unroll
    for (int m = 0; m < 4; ++m)
#pragma unroll
      for (int n = 0; n < 4; ++n) {
        acc[m][n] = mfma16(al[m], bh[n], acc[m][n]);
        acc[m][n] = mfma16(ah[m], bl[n], acc[m][n]);
        acc[m][n] = mfma16(ah[m], bh[n], acc[m][n]);
      }
    __syncthreads();
  }

#pragma unroll
  for (int m = 0; m < 4; ++m)
#pragma unroll
    for (int rr = 0; rr < 4; ++rr) {
      const long orow = brow + wr * 64 + m * 16 + (lane >> 4) * 4 + rr;
#pragma unroll
      for (int n = 0; n < 4; ++n) {
        const int gcol = bcol + wc * 64 + n * 16 + (lane & 15);
        C[orow * 512 + gcol] = fmaxf(acc[m][n][rr] + bias[gcol], 0.f);
      }
    }
}

// ---------- K/V repack: qkv[T][2560] -> Vt[bh][64][1024] (d-major) + Kp[bh][1024][64] ----------
__global__ __launch_bounds__(256) void cm_kvtrans(
    const unsigned short* __restrict__ qkv, unsigned short* __restrict__ Vt,
    unsigned short* __restrict__ Kp) {
  const int stile = blockIdx.x, bh = blockIdx.y;
  const int b = bh >> 4, h = bh & 15;
  const int tid = threadIdx.x;
  __shared__ __align__(16) unsigned short t[64][72];
  const int d0 = (tid & 7) * 8, sl = tid >> 3;
#pragma unroll
  for (int i = 0; i < 2; ++i) {
    const int s = sl + i * 32;
    const long src = (long)(b * 1024 + stile * 64 + s) * 2560 + h * 64 + d0;
    *(u32x4*)&t[s][d0] = *(const u32x4*)(qkv + src + 1536);
    *(u32x4*)(Kp + ((long)bh * 1024 + stile * 64 + s) * 64 + d0) =
        *(const u32x4*)(qkv + src + 512);
  }
  __syncthreads();
  const int s0 = (tid & 7) * 8, dl = tid >> 3;
#pragma unroll
  for (int i = 0; i < 2; ++i) {
    const int d = dl + i * 32;
    unsigned short vals[8];
#pragma unroll
    for (int j = 0; j < 8; ++j) vals[j] = t[s0 + j][d];
    u32x4 u;
    u.x = vals[0] | ((unsigned)vals[1] << 16);
    u.y = vals[2] | ((unsigned)vals[3] << 16);
    u.z = vals[4] | ((unsigned)vals[5] << 16);
    u.w = vals[6] | ((unsigned)vals[7] << 16);
    *(u32x4*)(Vt + (long)(bh * 64 + d) * 1024 + stile * 64 + s0) = u;
  }
}

// ---------- attention: per (q-tile of 64, b*h). Round-chunked unnormalized-PV ----------
// r17 final: score dbuf (1 barrier/round), K from packed Kp, in-place loads.
// Session ledger: reg-prefetch (r18 spilled, r19 neutral), LDS pipelining
// (r5/r13/r15 regressed) — this is the measured optimum of the family.
__global__ __launch_bounds__(256, 4) void cm_attn(
    const unsigned short* __restrict__ qkv,
    const unsigned short* __restrict__ Kp,
    const unsigned short* __restrict__ Vt,
    unsigned short* __restrict__ ao) {
  int flat = (int)blockIdx.x;                 // 1024 blocks
  flat = (flat & 7) * 128 + (flat >> 3);      // chunked XCD swizzle (1024 % 8 == 0)
  const int qt = flat & 15, bh = flat >> 4;
  const int b = bh >> 4, h = bh & 15, g = h >> 1;
  const int tid = threadIdx.x, wid = tid >> 6, lane = tid & 63;
  const int q0 = qt * 64;

  __shared__ __align__(16) unsigned short sc[2][64][132];  // dbuf exp(scores)
  __shared__ float rsum[4][64];
  __shared__ float rowrcp[64];

  bf16x8 bq[4][2];
#pragma unroll
  for (int nf = 0; nf < 4; ++nf)
#pragma unroll
    for (int ks = 0; ks < 2; ++ks)
      bq[nf][ks] = load_bf8(qkv + (long)(b * 1024 + q0 + nf * 16 + (lane & 15)) * 2560 +
                            g * 64 + ks * 32 + (lane >> 4) * 8);

  f32x4 oacc[4] = {};
  float ps[4] = {0.f, 0.f, 0.f, 0.f};
  const unsigned short* vtb = Vt + (long)bh * 64 * 1024;
  const unsigned short* kpb = Kp + (long)bh * 1024 * 64;

#pragma unroll 2
  for (int rnd = 0; rnd < 8; ++rnd) {
    const int cur = rnd & 1;
    // Phase 1: this wave's 32-key chunk -> exp -> sc[cur] + row-sum partials
    {
      const int kb = rnd * 128 + wid * 32;
      f32x4 acc[2][4] = {};
#pragma unroll
      for (int ks = 0; ks < 2; ++ks) {
        bf16x8 ak[2];
#pragma unroll
        for (int mf = 0; mf < 2; ++mf)
          ak[mf] = load_bf8(kpb + (kb + mf * 16 + (lane & 15)) * 64 +
                            ks * 32 + (lane >> 4) * 8);
#pragma unroll
        for (int mf = 0; mf < 2; ++mf)
#pragma unroll
          for (int nf = 0; nf < 4; ++nf)
            acc[mf][nf] = mfma16(ak[mf], bq[nf][ks], acc[mf][nf]);
      }
#pragma unroll
      for (int mf = 0; mf < 2; ++mf)
#pragma unroll
        for (int nf = 0; nf < 4; ++nf) {
          const int q = nf * 16 + (lane & 15);
          const int kl = wid * 32 + mf * 16 + (lane >> 4) * 4;
          float e0 = __expf(acc[mf][nf][0] * 0.125f);
          float e1 = __expf(acc[mf][nf][1] * 0.125f);
          float e2 = __expf(acc[mf][nf][2] * 0.125f);
          float e3 = __expf(acc[mf][nf][3] * 0.125f);
          ps[nf] += (e0 + e1) + (e2 + e3);
          u32x2 pk;
          pk.x = pack2bf(e0, e1);
          pk.y = pack2bf(e2, e3);
          *(u32x2*)&sc[cur][q][kl] = pk;
        }
    }
    __syncthreads();  // sc[cur] complete; also orders rnd's writes vs rnd-1's reads
    // Phase 2: PV over this round's 128 keys; wave owns d-cols [wid*16,+16)
#pragma unroll
    for (int k0 = 0; k0 < 128; k0 += 32) {
      const bf16x8 bv = load_bf8(vtb + (long)(wid * 16 + (lane & 15)) * 1024 +
                                 rnd * 128 + k0 + (lane >> 4) * 8);
#pragma unroll
      for (int m = 0; m < 4; ++m) {
        const bf16x8 ap = load_bf8(&sc[cur][m * 16 + (lane & 15)][k0 + (lane >> 4) * 8]);
        oacc[m] = mfma16(ap, bv, oacc[m]);
      }
    }
    // no barrier: next round writes sc[cur^1]
  }
  __syncthreads();

#pragma unroll
  for (int nf = 0; nf < 4; ++nf) {
    ps[nf] += __shfl_xor(ps[nf], 16);
    ps[nf] += __shfl_xor(ps[nf], 32);
  }
  if (lane < 16) {
#pragma unroll
    for (int nf = 0; nf < 4; ++nf) rsum[wid][lane + nf * 16] = ps[nf];
  }
  __syncthreads();
  if (tid < 64)
    rowrcp[tid] = 1.f / (rsum[0][tid] + rsum[1][tid] + rsum[2][tid] + rsum[3][tid]);
  __syncthreads();

#pragma unroll
  for (int m = 0; m < 4; ++m)
#pragma unroll
    for (int rr = 0; rr < 4; ++rr) {
      const int q = m * 16 + (lane >> 4) * 4 + rr;
      const int d = wid * 16 + (lane & 15);
      ao[(long)(b * 1024 + q0 + q) * 1024 + h * 64 + d] = f2bf(oacc[m][rr] * rowrcp[q]);
    }
}

// ---------- routing pick: gate-2 GEMV + softmax + top2 + renorm (NO atomics) ----------
__global__ __launch_bounds__(64) void cm_route_pick(
    const float* __restrict__ g1f, const float* __restrict__ gw2, const float* __restrict__ gb2,
    int* __restrict__ pick, int* __restrict__ slot_e, float* __restrict__ rwt) {
  const int t = blockIdx.x, lane = threadIdx.x;
  f32x4 a0 = *(const f32x4*)(g1f + (long)t * 512 + lane * 8);
  f32x4 a1 = *(const f32x4*)(g1f + (long)t * 512 + lane * 8 + 4);
  float logit[8];
#pragma unroll
  for (int e = 0; e < 8; ++e) {
    float s = 0.f;
#pragma unroll
    for (int j = 0; j < 4; ++j) {
      s += a0[j] * gw2[(lane * 8 + j) * 8 + e];
      s += a1[j] * gw2[(lane * 8 + 4 + j) * 8 + e];
    }
#pragma unroll
    for (int m = 32; m >= 1; m >>= 1) s += __shfl_xor(s, m);
    logit[e] = s + gb2[e];
  }
  float mx = logit[0];
#pragma unroll
  for (int e = 1; e < 8; ++e) mx = fmaxf(mx, logit[e]);
  float p[8], sum = 0.f;
#pragma unroll
  for (int e = 0; e < 8; ++e) { p[e] = __expf(logit[e] - mx); sum += p[e]; }
  const float rs = 1.f / sum;
#pragma unroll
  for (int e = 0; e < 8; ++e) p[e] *= rs;
  int i0 = 0;
#pragma unroll
  for (int e = 1; e < 8; ++e) if (p[e] > p[i0]) i0 = e;
  int i1 = (i0 == 0) ? 1 : 0;
#pragma unroll
  for (int e = 0; e < 8; ++e) if (e != i0 && p[e] > p[i1]) i1 = e;
  // reference: softmax AGAIN over the top-k *probabilities*
  const float w0 = 1.f / (1.f + __expf(p[i1] - p[i0]));
  if (lane == 0) {
    pick[t] = i0 | (i1 << 8);
    slot_e[t * 2] = i0; slot_e[t * 2 + 1] = i1;
    rwt[t * 2] = w0;    rwt[t * 2 + 1] = 1.f - w0;
  }
}

// ---------- routing place: wave-aggregated histogram + scatter (8 atomics/wave) ----------
__global__ __launch_bounds__(256) void cm_route_place(
    const int* __restrict__ pick, int* __restrict__ cnt,
    int* __restrict__ etok, int* __restrict__ slot_p) {
  const int t = blockIdx.x * 256 + threadIdx.x;
  const int lane = threadIdx.x & 63;
  const int pk = pick[t];
  const int p0 = pk & 15, p1 = (pk >> 8) & 15;
  const unsigned long long lt = ((unsigned long long)1 << lane) - 1;
  int my_r0 = 0, my_c0p1 = 0, my_r1 = 0, tot = 0;
#pragma unroll
  for (int e = 0; e < 8; ++e) {
    const unsigned long long m0 = __ballot(p0 == e);
    const unsigned long long m1 = __ballot(p1 == e);
    if (p0 == e) my_r0 = __popcll(m0 & lt);
    if (p1 == e) { my_c0p1 = __popcll(m0); my_r1 = __popcll(m1 & lt); }
    if (lane == e) tot = __popcll(m0) + __popcll(m1);
  }
  int base = 0;
  if (lane < 8 && tot > 0) base = atomicAdd(&cnt[lane], tot);
  const int b0 = __shfl(base, p0);
  const int b1 = __shfl(base, p1);
  const int pos0 = b0 + my_r0;
  const int pos1 = b1 + my_c0p1 + my_r1;
  etok[p0 * 4096 + pos0] = t;
  etok[p1 * 4096 + pos1] = t;
  slot_p[t * 2] = pos0;
  slot_p[t * 2 + 1] = pos1;
}

__global__ void cm_offs(const int* __restrict__ cnt, int* __restrict__ offs) {
  if (threadIdx.x == 0) {
    int s = 0;
#pragma unroll
    for (int e = 0; e < 8; ++e) { offs[e] = s; s += cnt[e]; }
  }
}

// ---------- combine: out = x2 + w0*eo[slot0] + w1*eo[slot1] ----------
__global__ __launch_bounds__(256) void cm_combine(
    const float* __restrict__ x2, const unsigned short* __restrict__ eo,
    const int* __restrict__ slot_e, const int* __restrict__ slot_p,
    const float* __restrict__ rwt, const int* __restrict__ offs,
    float* __restrict__ outp) {
  const int t = blockIdx.x, tid = threadIdx.x;
  const long r0 = (long)(offs[slot_e[t * 2]] + slot_p[t * 2]);
  const long r1 = (long)(offs[slot_e[t * 2 + 1]] + slot_p[t * 2 + 1]);
  const float w0 = rwt[t * 2], w1 = rwt[t * 2 + 1];
  const f32x4 xv = *(const f32x4*)(x2 + (long)t * 1024 + tid * 4);
  u32x2 u0 = *(const u32x2*)(eo + r0 * 1024 + tid * 4);
  u32x2 u1 = *(const u32x2*)(eo + r1 * 1024 + tid * 4);
  f32x4 o;
  o[0] = xv[0] + w0 * bf2f(u0.x & 0xffffu) + w1 * bf2f(u1.x & 0xffffu);
  o[1] = xv[1] + w0 * bf2f(u0.x >> 16) + w1 * bf2f(u1.x >> 16);
  o[2] = xv[2] + w0 * bf2f(u0.y & 0xffffu) + w1 * bf2f(u1.y & 0xffffu);
  o[3] = xv[3] + w0 * bf2f(u0.y >> 16) + w1 * bf2f(u1.y >> 16);
  *(f32x4*)(outp + (long)t * 1024 + tid * 4) = o;
}

extern "C" void kernel_launch(void* const* d_in, const int* in_sizes, int n_in,
                              void* d_out, int out_size, void* d_ws, size_t ws_size,
                              hipStream_t stream) {
  if (n_in < 21) return;
  const float* x    = (const float*)d_in[0];
  const float* wq   = (const float*)d_in[1];
  const float* bq   = (const float*)d_in[2];
  const float* wk   = (const float*)d_in[3];
  const float* bk   = (const float*)d_in[4];
  const float* wv   = (const float*)d_in[5];
  const float* bv   = (const float*)d_in[6];
  const float* wo   = (const float*)d_in[7];
  const float* bo   = (const float*)d_in[8];
  const float* ln1g = (const float*)d_in[9];
  const float* ln1b = (const float*)d_in[10];
  const float* ln2g = (const float*)d_in[11];
  const float* ln2b = (const float*)d_in[12];
  const float* gw1  = (const float*)d_in[13];
  const float* gb1  = (const float*)d_in[14];
  const float* gw2  = (const float*)d_in[15];
  const float* gb2  = (const float*)d_in[16];
  const float* ew1  = (const float*)d_in[17];
  const float* eb1  = (const float*)d_in[18];
  const float* ew2  = (const float*)d_in[19];
  const float* eb2  = (const float*)d_in[20];
  float* outp = (float*)d_out;

  char* ws = (char*)d_ws;
  size_t off = 0;
  auto carve = [&](size_t bytes) -> char* {
    char* p = ws + off;
    off += (bytes + 255) & ~(size_t)255;
    return p;
  };
  unsigned short* wqkvT = (unsigned short*)carve(2560l * 1024 * 2);
  unsigned short* woT   = (unsigned short*)carve(1024l * 1024 * 2);
  unsigned short* gw1hT = (unsigned short*)carve(512l * 1024 * 2);
  unsigned short* gw1lT = (unsigned short*)carve(512l * 1024 * 2);
  unsigned short* ew1T  = (unsigned short*)carve(8l * 2048 * 1024 * 2);
  unsigned short* ew2T  = (unsigned short*)carve(8l * 1024 * 2048 * 2);
  float* bqkv           = (float*)carve(2560 * 4);
  unsigned short* hbuf  = (unsigned short*)carve(4096l * 1024 * 2);
  unsigned short* qkvl  = (unsigned short*)carve(4096l * 2560 * 2);
  unsigned short* Vt    = (unsigned short*)carve(4096l * 1024 * 2);
  unsigned short* Kp    = (unsigned short*)carve(4096l * 1024 * 2);
  unsigned short* ao    = (unsigned short*)carve(4096l * 1024 * 2);
  unsigned short* h2    = (unsigned short*)carve(4096l * 1024 * 2);
  unsigned short* h2lo  = (unsigned short*)carve(4096l * 1024 * 2);
  int* cnt              = (int*)carve(8 * 4);
  int* offs             = (int*)carve(8 * 4);
  int* etok             = (int*)carve(8l * 4096 * 4);
  int* slot_e           = (int*)carve(8192 * 4);
  int* slot_p           = (int*)carve(8192 * 4);
  float* rwt            = (float*)carve(8192 * 4);
  int* pick             = (int*)carve(4096 * 4);
  unsigned short* hid   = (unsigned short*)carve(8192l * 2048 * 2);
  unsigned short* eo    = (unsigned short*)carve(8192l * 1024 * 2);
  if (off > ws_size) return;  // workspace too small -> fail loudly via validation
  float* x2 = outp;           // residual-1 result lives in d_out (rewritten every call)
  // dead-buffer reuse: Vt (8 MB) is consumed by cm_attn; gate hidden fp32 needs exactly 8 MB
  float* g1f = (float*)Vt;    // [4096][512] fp32 gate hidden

  (void)hipMemsetAsync(cnt, 0, 8 * 4, stream);
  (void)hipMemcpyAsync(bqkv, (const void*)bq, 512 * 4, hipMemcpyDeviceToDevice, stream);
  (void)hipMemcpyAsync(bqkv + 512, (const void*)bk, 1024 * 4, hipMemcpyDeviceToDevice, stream);
  (void)hipMemcpyAsync(bqkv + 1536, (const void*)bv, 1024 * 4, hipMemcpyDeviceToDevice, stream);

  cm_transpose<<<dim3(16, 32, 1), 256, 0, stream>>>(wq, wqkvT, 1024, 512, 0l, 0l);
  cm_transpose<<<dim3(32, 32, 1), 256, 0, stream>>>(wk, wqkvT + 512l * 1024, 1024, 1024, 0l, 0l);
  cm_transpose<<<dim3(32, 32, 1), 256, 0, stream>>>(wv, wqkvT + 1536l * 1024, 1024, 1024, 0l, 0l);
  cm_transpose<<<dim3(32, 32, 1), 256, 0, stream>>>(wo, woT, 1024, 1024, 0l, 0l);
  cm_transpose_split<<<dim3(16, 32, 1), 256, 0, stream>>>(gw1, gw1hT, gw1lT, 1024, 512);
  cm_transpose<<<dim3(64, 32, 8), 256, 0, stream>>>(ew1, ew1T, 1024, 2048, 1024l * 2048, 2048l * 1024);
  cm_transpose<<<dim3(32, 64, 8), 256, 0, stream>>>(ew2, ew2T, 2048, 1024, 2048l * 1024, 1024l * 2048);

  cm_ln<false><<<4096, 256, 0, stream>>>(x, ln1g, ln1b, hbuf, nullptr);
  cm_gemm_bt<EP_BF16, 0><<<dim3(20, 32, 1), 512, 0, stream>>>(
      hbuf, 1024, wqkvT, 0l, 1024, bqkv, 0, nullptr, qkvl, 2560, 4096, 1024,
      nullptr, nullptr, nullptr);
  cm_kvtrans<<<dim3(16, 64, 1), 256, 0, stream>>>(qkvl, Vt, Kp);
  cm_attn<<<dim3(1024, 1, 1), 256, 0, stream>>>(qkvl, Kp, Vt, ao);
  cm_gemm_bt<EP_RES_F32, 0><<<dim3(8, 32, 1), 512, 0, stream>>>(
      ao, 1024, woT, 0l, 1024, bo, 0, x, x2, 1024, 4096, 1024,
      nullptr, nullptr, nullptr);
  cm_ln<true><<<4096, 256, 0, stream>>>(x2, ln2g, ln2b, h2, h2lo);

  // --- gate: split-bf16 MFMA GEMM (near-fp32 accuracy), pick + aggregated place ---
  cm_gemm_gate<<<dim3(4, 32, 1), 256, 0, stream>>>(h2, h2lo, gw1hT, gw1lT, gb1, g1f);
  cm_route_pick<<<4096, 64, 0, stream>>>(g1f, gw2, gb2, pick, slot_e, rwt);
  cm_route_place<<<16, 256, 0, stream>>>(pick, cnt, etok, slot_p);
  cm_offs<<<1, 64, 0, stream>>>(cnt, offs);

  cm_gemm_bt<EP_GELU, 1><<<dim3(16, 32, 8), 512, 0, stream>>>(
      h2, 1024, ew1T, 2048l * 1024, 1024, eb1, 2048, nullptr, hid, 2048, 4096, 1024,
      cnt, offs, etok);
  cm_gemm_bt<EP_BF16, 2><<<dim3(8, 32, 8), 512, 0, stream>>>(
      hid, 2048, ew2T, 1024l * 2048, 2048, eb2, 1024, nullptr, eo, 1024, 4096, 2048,
      cnt, offs, nullptr);
  cm_combine<<<4096, 256, 0, stream>>>(x2, eo, slot_e, slot_p, rwt, offs, outp);
}